// Round 3
// baseline (327.303 us; speedup 1.0000x reference)
//
#include <hip/hip_runtime.h>
#include <hip/hip_bf16.h>
#include <math.h>

typedef __attribute__((ext_vector_type(8))) short bf16x8;
typedef __attribute__((ext_vector_type(4))) float f32x4;

#define SEQ 1024
#define DIM 768
#define NH 12
#define HD 64

// ws layout (BYTE offsets) — total ~6.38 MB + flag:
//   Qb   bf16 [12][1024][64]  @ 0
//   Kb   bf16 [12][1024][64]  @ 1572864
//   Vt   bf16 [768][1024]     @ 3145728   (v transposed: [h*64+e][l])
//   opre bf16 [1024][768]     @ 4718592
//   G    f32  [1024][36]      @ 6291456
//   scal f32  5*[12][1024]    @ 6438912   (si, es, al, be, ga)
//   flag int                  @ 6684672   (1 => inputs are f32, 0 => bf16)
// u (bf16 [12][1024][64]) borrows d_out as scratch; k_oproj overwrites it last.

__device__ __forceinline__ float wave_reduce_sum(float v) {
    for (int off = 1; off < 64; off <<= 1) v += __shfl_xor(v, off);
    return v;
}

__device__ __forceinline__ short f2bs(float x) {
    __hip_bfloat16 h = __float2bfloat16(x);
    return *reinterpret_cast<short*>(&h);
}

template<bool F32>
__device__ __forceinline__ bf16x8 load8(const void* p, size_t idx) {
    if constexpr (F32) {
        const float* f = (const float*)p + idx;
        float4 a = *(const float4*)f;
        float4 b = *(const float4*)(f + 4);
        bf16x8 r;
        r[0] = f2bs(a.x); r[1] = f2bs(a.y); r[2] = f2bs(a.z); r[3] = f2bs(a.w);
        r[4] = f2bs(b.x); r[5] = f2bs(b.y); r[6] = f2bs(b.z); r[7] = f2bs(b.w);
        return r;
    } else {
        return *(const bf16x8*)((const short*)p + idx);
    }
}

__device__ __forceinline__ float loadS(const void* p, int idx, int f32m) {
    return f32m ? ((const float*)p)[idx] : (float)((const __hip_bfloat16*)p)[idx];
}

// ---------------- K0: detect input dtype ----------------
// If data is f32, the LOW 16-bit word of each u32 is random mantissa bits ->
// interpreted as bf16 it has a uniform exponent (≈8% land in a sane range).
// If data is bf16 (values ~N(0,1)), the low word IS a real value (≈100% sane).
__global__ __launch_bounds__(256) void k_detect(const unsigned int* __restrict__ Xw,
                                                int* __restrict__ flag)
{
    int tid = threadIdx.x;
    __shared__ int cnt[4];
    int local = 0;
    for (int i = tid; i < 1024; i += 256) {
        unsigned int lo = (Xw[i] & 0xffffu) << 16;
        float v = __uint_as_float(lo);
        float a = fabsf(v);
        if (a >= 1e-4f && a <= 100.f) local++;
    }
    for (int off = 1; off < 64; off <<= 1) local += __shfl_xor(local, off);
    if ((tid & 63) == 0) cnt[tid >> 6] = local;
    __syncthreads();
    if (tid == 0) {
        int tot = cnt[0] + cnt[1] + cnt[2] + cnt[3];
        *flag = (tot < 512) ? 1 : 0;
    }
}

// ---------------- K1: all projections, bf16 outputs in attention-ready layouts ----
template<bool F32>
__global__ __launch_bounds__(256) void k_proj(const void* __restrict__ X,
    const void* __restrict__ W0, const void* __restrict__ W1,
    const void* __restrict__ W2, const void* __restrict__ W3,
    const void* __restrict__ W4, const int* __restrict__ flag,
    __hip_bfloat16* __restrict__ Qb, __hip_bfloat16* __restrict__ Kb,
    __hip_bfloat16* __restrict__ Vt, __hip_bfloat16* __restrict__ Ub,
    float* __restrict__ G)
{
    if (*flag != (F32 ? 1 : 0)) return;
    int rt = blockIdx.x, ct = blockIdx.y, mat = blockIdx.z;
    if (mat == 4 && ct >= 3) return;
    const void* W = (mat==0)?W0:(mat==1)?W1:(mat==2)?W2:(mat==3)?W3:W4;
    int wv = threadIdx.x >> 6, lane = threadIdx.x & 63;
    int g = lane >> 4, n = lane & 15;
    int arow = rt*64 + wv*16 + n;       // A row (m = lane&15)
    int c    = ct*16 + n;               // B row (n = lane&15) = output col
    bool colok = (mat < 4) || (c < 36);
    size_t abase = (size_t)arow*DIM + g*8;
    size_t bbase = (size_t)c*DIM + g*8;
    f32x4 acc = {0.f, 0.f, 0.f, 0.f};
    for (int k = 0; k < DIM; k += 32) {
        bf16x8 a = load8<F32>(X, abase + k);
        bf16x8 b = {0,0,0,0,0,0,0,0};
        if (colok) b = load8<F32>(W, bbase + k);
        acc = __builtin_amdgcn_mfma_f32_16x16x32_bf16(a, b, acc, 0, 0, 0);
    }
    // C/D: col = lane&15, row = (lane>>4)*4 + r
    int m0 = rt*64 + wv*16 + g*4;
    if (mat == 2) {
        for (int r = 0; r < 4; ++r)
            Vt[(size_t)c*SEQ + m0 + r] = __float2bfloat16(acc[r]);
    } else if (mat < 4) {
        __hip_bfloat16* dst = (mat==0) ? Qb : (mat==1) ? Kb : Ub;
        size_t base = ((size_t)(c >> 6)*SEQ)*HD + (c & 63);
        for (int r = 0; r < 4; ++r)
            dst[base + (size_t)(m0 + r)*HD] = __float2bfloat16(acc[r]);
    } else if (c < 36) {
        for (int r = 0; r < 4; ++r) G[(size_t)(m0 + r)*36 + c] = acc[r];
    }
}

// ---------------- K2: per-head cumsum(u) -> s_i, smax, E/P scans -> alpha/beta/gamma
__global__ __launch_bounds__(1024) void k_scan(const __hip_bfloat16* __restrict__ Ub,
    const float* __restrict__ G, const void* __restrict__ pmu,
    const void* __restrict__ plt, const int* __restrict__ flag,
    float* __restrict__ si_, float* __restrict__ es_, float* __restrict__ al_,
    float* __restrict__ be_, float* __restrict__ ga_)
{
    int h = blockIdx.x;
    int tid = threadIdx.x, wv = tid >> 6, lane = tid & 63;
    __shared__ float sbuf[SEQ], ebuf[SEQ], g1b[SEQ], ghb[SEQ];
    __shared__ float stot[16][64];
    __shared__ float wmax[16];
    __shared__ float smax_s;

    int f32m = *flag;
    float ltv = loadS(plt, h, f32m);
    ltv = fminf(fmaxf(ltv, -50.f), 30.f);
    float ltau = expf(ltv);
    float mu = loadS(pmu, h*HD + lane, f32m);

    const __hip_bfloat16* up = Ub + ((size_t)h*SEQ + wv*64)*HD + lane;
    // phase 1: wave-local vector sums of u
    float Ul = 0.f;
    for (int i = 0; i < 64; ++i) Ul += (float)up[(size_t)i*HD];
    stot[wv][lane] = Ul;
    __syncthreads();
    // phase 2: cross-wave exclusive prefix + prior
    float pre = ltau * mu;
    for (int w2 = 0; w2 < wv; ++w2) pre += stot[w2][lane];
    // phase 3: inclusive running cumsum, s_i via 64-lane dot reduce
    float V = pre;
    for (int i = 0; i < 64; ++i) {
        float uv = (float)up[(size_t)i*HD];
        V += uv;
        int l = wv*64 + i;
        float bar = V / (ltau + (float)(l + 1));
        float p = wave_reduce_sum(uv * bar);
        if (lane == 0) sbuf[l] = -p * 0.125f;   // / sqrt(64)
    }
    __syncthreads();
    // s_max over L
    float v = sbuf[tid];
    float vm = v;
    for (int off = 1; off < 64; off <<= 1) vm = fmaxf(vm, __shfl_xor(vm, off));
    if (lane == 0) wmax[wv] = vm;
    __syncthreads();
    if (wv == 0) {
        float mm = (lane < 16) ? wmax[lane] : -1e30f;
        for (int off = 1; off < 16; off <<= 1) mm = fmaxf(mm, __shfl_xor(mm, off));
        if (lane == 0) smax_s = mm;
    }
    __syncthreads();
    float smax = smax_s;
    float ev = expf(fminf(v - smax, 0.f));
    ebuf[tid] = ev;
    float gg1 = G[(size_t)tid*36 + h*3 + 0];
    float ggh = G[(size_t)tid*36 + h*3 + 1];
    g1b[tid] = 1.f / (1.f + expf(-gg1));
    ghb[tid] = 1.f / (1.f + expf(-ggh));
    si_[h*SEQ + tid] = v;
    es_[h*SEQ + tid] = ev;
    __syncthreads();
    // E_t / P_t inclusive scans + alpha/beta/gamma (wave 0, lane-parallel)
    if (wv == 0) {
        int base = lane * 16;
        float se = 0.f, ss = 0.f;
        for (int i = 0; i < 16; ++i) { se += ebuf[base + i]; ss += sbuf[base + i]; }
        float pe = se, ps = ss;
        for (int off = 1; off < 64; off <<= 1) {
            float t1 = __shfl_up(pe, off), t2 = __shfl_up(ps, off);
            if (lane >= off) { pe += t1; ps += t2; }
        }
        float E = pe - se, P = ps - ss;   // exclusive prefixes
        for (int i = 0; i < 16; ++i) {
            int l = base + i;
            E += ebuf[l]; P += sbuf[l];
            float t = (float)(l + 1);
            float s1 = g1b[l], sh = ghb[l];
            float a = sh / (E + 1e-12f);
            float b = (s1 - sh) / t;
            float gm = -((b * P + sh) / t);
            al_[h*SEQ + l] = a;
            be_[h*SEQ + l] = b;
            ga_[h*SEQ + l] = gm;
        }
    }
}

// ---------------- K3: in-place RoPE + L2 normalize on Qb/Kb ----------------
__global__ __launch_bounds__(256) void k_rope(__hip_bfloat16* __restrict__ Qb,
                                              __hip_bfloat16* __restrict__ Kb)
{
    int wv = threadIdx.x >> 6, lane = threadIdx.x & 63;
    int idx = blockIdx.x * 4 + wv;        // idx = h*1024 + l
    int l = idx & 1023;
    size_t o = (size_t)idx*HD + lane;
    float qv = (float)Qb[o], kv = (float)Kb[o];
    // repeat-style table: cos_full[j] = cos(l * inv[j>>1]); rotate_half pairs j <-> j^32
    int i2 = lane >> 1;
    float inv = expf((float)i2 * (-9.210340371976184f / 32.f));  // 10000^{-i2/32}
    float ang = (float)l * inv;
    float c = cosf(ang), s = sinf(ang);
    float qp = __shfl(qv, lane ^ 32);
    float kp = __shfl(kv, lane ^ 32);
    float qrot = (lane < 32) ? -qp : qp;
    float krot = (lane < 32) ? -kp : kp;
    float qr = qv*c + qrot*s;
    float kr = kv*c + krot*s;
    float qn = wave_reduce_sum(qr*qr);
    float kn = wave_reduce_sum(kr*kr);
    qr = qr / fmaxf(sqrtf(qn), 1e-12f);
    kr = kr / fmaxf(sqrtf(kn), 1e-12f);
    Qb[o] = __float2bfloat16(qr);
    Kb[o] = __float2bfloat16(kr);
}

// ---------------- K4: causal rank-3-weighted linear attention + LayerNorm ------
__global__ __launch_bounds__(256) void k_attn(const __hip_bfloat16* __restrict__ Qb,
    const __hip_bfloat16* __restrict__ Kb, const __hip_bfloat16* __restrict__ Vt,
    const float* __restrict__ si_, const float* __restrict__ es_,
    const float* __restrict__ al_, const float* __restrict__ be_,
    const float* __restrict__ ga_, __hip_bfloat16* __restrict__ opre)
{
    int qt = blockIdx.x, h = blockIdx.y;
    int wv = threadIdx.x >> 6, lane = threadIdx.x & 63;
    int g = lane >> 4, n = lane & 15;
    __shared__ __hip_bfloat16 P[4][16][72];   // per-wave 16x64 weighted scores (+pad)
    int m0 = qt*64 + wv*16;
    const short* qrow = (const short*)Qb + ((size_t)h*SEQ + m0 + n)*HD + g*8;
    bf16x8 qa0 = *(const bf16x8*)qrow;
    bf16x8 qa1 = *(const bf16x8*)(qrow + 32);
    const float* al = al_ + h*SEQ;
    const float* be = be_ + h*SEQ;
    const float* ga = ga_ + h*SEQ;
    const float* es = es_ + h*SEQ;
    const float* si = si_ + h*SEQ;
    float A_[4], B_[4], G_[4];
    for (int r = 0; r < 4; ++r) {
        int m = m0 + g*4 + r;
        A_[r] = al[m]; B_[r] = be[m]; G_[r] = ga[m];
    }
    f32x4 acco[4];
    for (int et = 0; et < 4; ++et) acco[et] = (f32x4){0.f,0.f,0.f,0.f};

    for (int jt = 0; jt <= qt; ++jt) {
        int j0 = jt*64;
        for (int ct = 0; ct < 4; ++ct) {
            const short* krow = (const short*)Kb + ((size_t)h*SEQ + j0 + ct*16 + n)*HD + g*8;
            bf16x8 kb0 = *(const bf16x8*)krow;
            bf16x8 kb1 = *(const bf16x8*)(krow + 32);
            f32x4 sacc = {0.f,0.f,0.f,0.f};
            sacc = __builtin_amdgcn_mfma_f32_16x16x32_bf16(qa0, kb0, sacc, 0, 0, 0);
            sacc = __builtin_amdgcn_mfma_f32_16x16x32_bf16(qa1, kb1, sacc, 0, 0, 0);
            int j = j0 + ct*16 + n;
            float ej = es[j], sj = si[j];
            for (int r = 0; r < 4; ++r) {
                int m = m0 + g*4 + r;
                float w = (j <= m) ? (A_[r]*ej + B_[r]*sj + G_[r]) : 0.f;
                P[wv][g*4 + r][ct*16 + n] = __float2bfloat16(w * sacc[r]);
            }
        }
        __syncthreads();
        const short* vb = (const short*)Vt + (size_t)h*HD*SEQ;
        for (int et = 0; et < 4; ++et) {
            for (int sub = 0; sub < 2; ++sub) {
                bf16x8 pa = *(const bf16x8*)(&P[wv][n][sub*32 + g*8]);
                bf16x8 vfr = *(const bf16x8*)(vb + (size_t)(et*16 + n)*SEQ + j0 + sub*32 + g*8);
                acco[et] = __builtin_amdgcn_mfma_f32_16x16x32_bf16(pa, vfr, acco[et], 0, 0, 0);
            }
        }
        __syncthreads();
    }
    // fused LayerNorm over head dim (row m = 16 lanes sharing g; 4 regs x 4 et)
    for (int r = 0; r < 4; ++r) {
        float x0 = acco[0][r], x1 = acco[1][r], x2 = acco[2][r], x3 = acco[3][r];
        float sm = x0 + x1 + x2 + x3;
        float sq = x0*x0 + x1*x1 + x2*x2 + x3*x3;
        for (int off = 1; off < 16; off <<= 1) {
            sm += __shfl_xor(sm, off);
            sq += __shfl_xor(sq, off);
        }
        float mu = sm * (1.f/64.f);
        float var = fmaxf(sq * (1.f/64.f) - mu*mu, 0.f);
        float invs = rsqrtf(var + 1e-5f);
        int m = m0 + g*4 + r;
        __hip_bfloat16* orow = opre + (size_t)m*DIM + h*HD;
        for (int et = 0; et < 4; ++et)
            orow[et*16 + n] = __float2bfloat16((acco[et][r] - mu) * invs);
    }
}

// ---------------- K5: output projection (overwrites d_out, which held u scratch) --
template<bool F32>
__global__ __launch_bounds__(256) void k_oproj(const __hip_bfloat16* __restrict__ A,
    const void* __restrict__ Wo, const int* __restrict__ flag, void* __restrict__ out)
{
    if (*flag != (F32 ? 1 : 0)) return;
    int rt = blockIdx.x, ct = blockIdx.y;
    int wv = threadIdx.x >> 6, lane = threadIdx.x & 63;
    int g = lane >> 4, n = lane & 15;
    int arow = rt*64 + wv*16 + n;
    int bcol = ct*16 + n;
    const short* Ar = (const short*)A + (size_t)arow*DIM + g*8;
    size_t bbase = (size_t)bcol*DIM + g*8;
    f32x4 acc = {0.f,0.f,0.f,0.f};
    for (int k = 0; k < DIM; k += 32) {
        bf16x8 a = *(const bf16x8*)(Ar + k);
        bf16x8 b = load8<F32>(Wo, bbase + k);
        acc = __builtin_amdgcn_mfma_f32_16x16x32_bf16(a, b, acc, 0, 0, 0);
    }
    int orow = rt*64 + wv*16 + g*4;
    for (int r = 0; r < 4; ++r) {
        size_t oi = (size_t)(orow + r)*DIM + ct*16 + n;
        if constexpr (F32) ((float*)out)[oi] = acc[r];
        else ((__hip_bfloat16*)out)[oi] = __float2bfloat16(acc[r]);
    }
}

extern "C" void kernel_launch(void* const* d_in, const int* in_sizes, int n_in,
                              void* d_out, int out_size, void* d_ws, size_t ws_size,
                              hipStream_t stream) {
    const void* X   = d_in[0];
    const void* Wq  = d_in[1];
    const void* Wk  = d_in[2];
    const void* Wv  = d_in[3];
    const void* Wu  = d_in[4];
    const void* Wg  = d_in[5];
    const void* Wo  = d_in[6];
    const void* pmu = d_in[7];
    const void* plt = d_in[8];

    char* w = (char*)d_ws;
    __hip_bfloat16* Qb   = (__hip_bfloat16*)(w + 0);
    __hip_bfloat16* Kb   = (__hip_bfloat16*)(w + 1572864);
    __hip_bfloat16* Vt   = (__hip_bfloat16*)(w + 3145728);
    __hip_bfloat16* opre = (__hip_bfloat16*)(w + 4718592);
    float*          G    = (float*)(w + 6291456);
    float*          si_  = (float*)(w + 6438912);
    float*          es_  = si_ + NH*SEQ;
    float*          al_  = es_ + NH*SEQ;
    float*          be_  = al_ + NH*SEQ;
    float*          ga_  = be_ + NH*SEQ;
    int*            flag = (int*)(w + 6684672);
    __hip_bfloat16* Ub   = (__hip_bfloat16*)d_out;   // scratch; k_oproj overwrites last

    hipLaunchKernelGGL(k_detect, dim3(1), dim3(256), 0, stream,
                       (const unsigned int*)X, flag);
    hipLaunchKernelGGL((k_proj<false>), dim3(16, 48, 5), dim3(256), 0, stream,
                       X, Wq, Wk, Wv, Wu, Wg, flag, Qb, Kb, Vt, Ub, G);
    hipLaunchKernelGGL((k_proj<true>), dim3(16, 48, 5), dim3(256), 0, stream,
                       X, Wq, Wk, Wv, Wu, Wg, flag, Qb, Kb, Vt, Ub, G);
    hipLaunchKernelGGL(k_scan, dim3(NH), dim3(1024), 0, stream,
                       Ub, G, pmu, plt, flag, si_, es_, al_, be_, ga_);
    hipLaunchKernelGGL(k_rope, dim3(3072), dim3(256), 0, stream, Qb, Kb);
    hipLaunchKernelGGL(k_attn, dim3(16, NH), dim3(256), 0, stream,
                       Qb, Kb, Vt, si_, es_, al_, be_, ga_, opre);
    hipLaunchKernelGGL((k_oproj<false>), dim3(16, 48), dim3(256), 0, stream,
                       opre, Wo, flag, d_out);
    hipLaunchKernelGGL((k_oproj<true>), dim3(16, 48), dim3(256), 0, stream,
                       opre, Wo, flag, d_out);
}

// Round 4
// 236.733 us; speedup vs baseline: 1.3826x; 1.3826x over previous
//
#include <hip/hip_runtime.h>
#include <hip/hip_bf16.h>
#include <math.h>

typedef __attribute__((ext_vector_type(8))) short bf16x8;
typedef __attribute__((ext_vector_type(4))) float f32x4;

#define SEQ 1024
#define DIM 768
#define NH 12
#define HD 64

// ws layout (BYTE offsets) — total 6,684,672 B (proven size):
//   Qb   bf16 [12][1024][64]  @ 0
//   Kb   bf16 [12][1024][64]  @ 1572864
//   Vt   bf16 [768][1024]     @ 3145728   (v transposed: [h*64+e][l])
//   opre bf16 [1024][768]     @ 4718592
//   G    f32  [1024][36]      @ 6291456
//   scal f32  5*[12][1024]    @ 6438912   (si, es, al, be, ga)
// u (bf16 [12][1024][64]) borrows d_out as scratch; k_oproj overwrites it last.

__device__ __forceinline__ float wave_reduce_sum(float v) {
    for (int off = 1; off < 64; off <<= 1) v += __shfl_xor(v, off);
    return v;
}
__device__ __forceinline__ short f2bs(float x) {
    __hip_bfloat16 h = __float2bfloat16(x);
    return *reinterpret_cast<short*>(&h);
}
__device__ __forceinline__ bf16x8 cvt8(const float* __restrict__ s) {
    float4 a = *(const float4*)s, b = *(const float4*)(s + 4);
    bf16x8 r;
    r[0]=f2bs(a.x); r[1]=f2bs(a.y); r[2]=f2bs(a.z); r[3]=f2bs(a.w);
    r[4]=f2bs(b.x); r[5]=f2bs(b.y); r[6]=f2bs(b.z); r[7]=f2bs(b.w);
    return r;
}

// ---------------- K1: 5 projections, LDS-tiled 128x128 GEMM, f32->bf16 at staging
// LDS tiles stored as 16B chunks with XOR swizzle: logical (row, chunk c) at
// physical chunk c ^ (row&7)  -> aligned ds_read_b128, ~2-way max conflicts.
__global__ __launch_bounds__(256, 2) void k_proj5(const float* __restrict__ X,
    const float* __restrict__ Wq, const float* __restrict__ Wk,
    const float* __restrict__ Wv, const float* __restrict__ Wu,
    const float* __restrict__ Wg,
    __hip_bfloat16* __restrict__ Qb, __hip_bfloat16* __restrict__ Kb,
    __hip_bfloat16* __restrict__ Vt, __hip_bfloat16* __restrict__ Ub,
    float* __restrict__ G)
{
    int rt = blockIdx.x, ct = blockIdx.y, mat = blockIdx.z;
    if (mat == 4 && ct != 0) return;
    const float* W = (mat==0)?Wq:(mat==1)?Wk:(mat==2)?Wv:(mat==3)?Wu:Wg;
    int Brows = (mat==4) ? 36 : DIM;
    __shared__ short As[128*64], Bs[128*64];
    int tid = threadIdx.x;
    int wv = tid>>6, lane = tid&63, g = lane>>4, n = lane&15;
    int wm = wv>>1, wn = wv&1;
    int sch = tid & 7, srow = tid >> 3;       // staging: 8 chunks x 32 rows/pass
    f32x4 acc[4][4];
    for (int i=0;i<4;++i) for (int j=0;j<4;++j) acc[i][j] = (f32x4){0,0,0,0};

    for (int k0 = 0; k0 < DIM; k0 += 64) {
        for (int p = 0; p < 4; ++p) {
            int r = p*32 + srow;
            bf16x8 va = cvt8(X + (size_t)(rt*128 + r)*DIM + k0 + sch*8);
            *(bf16x8*)(&As[(r*8 + (sch ^ (r&7)))*8]) = va;
            int gr = ct*128 + r; if (gr >= Brows) gr = Brows - 1;   // gate clamp
            bf16x8 vb = cvt8(W + (size_t)gr*DIM + k0 + sch*8);
            *(bf16x8*)(&Bs[(r*8 + (sch ^ (r&7)))*8]) = vb;
        }
        __syncthreads();
        for (int ks = 0; ks < 2; ++ks) {
            bf16x8 af[4], bfr[4];
            int q = ks*4 + g;
            for (int i=0;i<4;++i) {
                int row = wm*64 + i*16 + n;
                af[i] = *(const bf16x8*)(&As[(row*8 + (q ^ (n&7)))*8]);
            }
            for (int j=0;j<4;++j) {
                int row = wn*64 + j*16 + n;
                bfr[j] = *(const bf16x8*)(&Bs[(row*8 + (q ^ (n&7)))*8]);
            }
            for (int i=0;i<4;++i)
                for (int j=0;j<4;++j)
                    acc[i][j] = __builtin_amdgcn_mfma_f32_16x16x32_bf16(af[i], bfr[j], acc[i][j], 0,0,0);
        }
        __syncthreads();
    }
    // C/D: col = lane&15, row = (lane>>4)*4 + r
    for (int i=0;i<4;++i) for (int j=0;j<4;++j) for (int r=0;r<4;++r) {
        int row = rt*128 + wm*64 + i*16 + g*4 + r;
        int col = ct*128 + wn*64 + j*16 + n;
        float v = acc[i][j][r];
        if (mat == 2) {
            Vt[(size_t)col*SEQ + row] = __float2bfloat16(v);
        } else if (mat == 4) {
            if (col < 36) G[(size_t)row*36 + col] = v;
        } else {
            __hip_bfloat16* dst = (mat==0)?Qb:(mat==1)?Kb:Ub;
            dst[((size_t)(col>>6)*SEQ + row)*HD + (col&63)] = __float2bfloat16(v);
        }
    }
}

// ---------------- K2: per-head cumsum(u) -> s_i, smax, E/P scans -> alpha/beta/gamma
__global__ __launch_bounds__(1024) void k_scan(const __hip_bfloat16* __restrict__ Ub,
    const float* __restrict__ G, const float* __restrict__ pmu,
    const float* __restrict__ plt,
    float* __restrict__ si_, float* __restrict__ es_, float* __restrict__ al_,
    float* __restrict__ be_, float* __restrict__ ga_)
{
    int h = blockIdx.x;
    int tid = threadIdx.x, wv = tid >> 6, lane = tid & 63;
    __shared__ float sbuf[SEQ], ebuf[SEQ], g1b[SEQ], ghb[SEQ];
    __shared__ float stot[16][64];
    __shared__ float wmax[16];
    __shared__ float smax_s;

    float ltv = fminf(fmaxf(plt[h], -50.f), 30.f);
    float ltau = expf(ltv);
    float mu = pmu[h*HD + lane];

    const __hip_bfloat16* up = Ub + ((size_t)h*SEQ + wv*64)*HD + lane;
    float Ul = 0.f;
    for (int i = 0; i < 64; ++i) Ul += (float)up[(size_t)i*HD];
    stot[wv][lane] = Ul;
    __syncthreads();
    float pre = ltau * mu;
    for (int w2 = 0; w2 < wv; ++w2) pre += stot[w2][lane];
    float V = pre;
    for (int i = 0; i < 64; ++i) {
        float uv = (float)up[(size_t)i*HD];
        V += uv;
        int l = wv*64 + i;
        float bar = V / (ltau + (float)(l + 1));
        float p = wave_reduce_sum(uv * bar);
        if (lane == 0) sbuf[l] = -p * 0.125f;   // / sqrt(64)
    }
    __syncthreads();
    float v = sbuf[tid];
    float vm = v;
    for (int off = 1; off < 64; off <<= 1) vm = fmaxf(vm, __shfl_xor(vm, off));
    if (lane == 0) wmax[wv] = vm;
    __syncthreads();
    if (wv == 0) {
        float mm = (lane < 16) ? wmax[lane] : -1e30f;
        for (int off = 1; off < 16; off <<= 1) mm = fmaxf(mm, __shfl_xor(mm, off));
        if (lane == 0) smax_s = mm;
    }
    __syncthreads();
    float ev = expf(fminf(v - smax_s, 0.f));
    ebuf[tid] = ev;
    g1b[tid] = 1.f / (1.f + expf(-G[(size_t)tid*36 + h*3 + 0]));
    ghb[tid] = 1.f / (1.f + expf(-G[(size_t)tid*36 + h*3 + 1]));
    si_[h*SEQ + tid] = v;
    es_[h*SEQ + tid] = ev;
    __syncthreads();
    if (wv == 0) {
        int base = lane * 16;
        float se = 0.f, ss = 0.f;
        for (int i = 0; i < 16; ++i) { se += ebuf[base + i]; ss += sbuf[base + i]; }
        float pe = se, ps = ss;
        for (int off = 1; off < 64; off <<= 1) {
            float t1 = __shfl_up(pe, off), t2 = __shfl_up(ps, off);
            if (lane >= off) { pe += t1; ps += t2; }
        }
        float E = pe - se, P = ps - ss;   // exclusive prefixes
        for (int i = 0; i < 16; ++i) {
            int l = base + i;
            E += ebuf[l]; P += sbuf[l];
            float t = (float)(l + 1);
            float s1 = g1b[l], sh = ghb[l];
            float a = sh / (E + 1e-12f);
            float b = (s1 - sh) / t;
            float gm = -((b * P + sh) / t);
            al_[h*SEQ + l] = a;
            be_[h*SEQ + l] = b;
            ga_[h*SEQ + l] = gm;
        }
    }
}

// ---------------- K3: in-place RoPE + L2 normalize on Qb/Kb ----------------
__global__ __launch_bounds__(256) void k_rope(__hip_bfloat16* __restrict__ Qb,
                                              __hip_bfloat16* __restrict__ Kb)
{
    int wv = threadIdx.x >> 6, lane = threadIdx.x & 63;
    int idx = blockIdx.x * 4 + wv;        // idx = h*1024 + l
    int l = idx & 1023;
    size_t o = (size_t)idx*HD + lane;
    float qv = (float)Qb[o], kv = (float)Kb[o];
    int i2 = lane >> 1;
    float inv = expf((float)i2 * (-9.210340371976184f / 32.f));  // 10000^{-i2/32}
    float ang = (float)l * inv;
    float c = cosf(ang), s = sinf(ang);
    float qp = __shfl(qv, lane ^ 32);
    float kp = __shfl(kv, lane ^ 32);
    float qrot = (lane < 32) ? -qp : qp;
    float krot = (lane < 32) ? -kp : kp;
    float qr = qv*c + qrot*s;
    float kr = kv*c + krot*s;
    float qn = wave_reduce_sum(qr*qr);
    float kn = wave_reduce_sum(kr*kr);
    qr = qr / fmaxf(sqrtf(qn), 1e-12f);
    kr = kr / fmaxf(sqrtf(kn), 1e-12f);
    Qb[o] = __float2bfloat16(qr);
    Kb[o] = __float2bfloat16(kr);
}

// ---------------- K4: causal weighted linear attention + LayerNorm -------------
// Barrier-free: each WAVE owns one 16-row q-tile (tile = blockIdx.x + 16*wv for
// load balance); P round-trips through per-wave XOR-swizzled LDS — only
// wave-internal lgkmcnt ordering needed, no __syncthreads.
__global__ __launch_bounds__(256) void k_attn(const __hip_bfloat16* __restrict__ Qb,
    const __hip_bfloat16* __restrict__ Kb, const __hip_bfloat16* __restrict__ Vt,
    const float* __restrict__ si_, const float* __restrict__ es_,
    const float* __restrict__ al_, const float* __restrict__ be_,
    const float* __restrict__ ga_, __hip_bfloat16* __restrict__ opre)
{
    int h = blockIdx.y;
    int wv = threadIdx.x >> 6, lane = threadIdx.x & 63;
    int g = lane >> 4, n = lane & 15;
    int t = blockIdx.x + 16*wv;           // q-tile index (16 rows)
    __shared__ short P[4][16*64];
    short* Pw = P[wv];
    int m0 = t*16;
    const short* qrow = (const short*)Qb + ((size_t)h*SEQ + m0 + n)*HD + g*8;
    bf16x8 qa0 = *(const bf16x8*)qrow;
    bf16x8 qa1 = *(const bf16x8*)(qrow + 32);
    const float* al = al_ + h*SEQ;
    const float* be = be_ + h*SEQ;
    const float* ga = ga_ + h*SEQ;
    const float* es = es_ + h*SEQ;
    const float* si = si_ + h*SEQ;
    float A_[4], B_[4], G_[4];
    for (int r = 0; r < 4; ++r) {
        int m = m0 + g*4 + r;
        A_[r] = al[m]; B_[r] = be[m]; G_[r] = ga[m];
    }
    f32x4 acco[4];
    for (int et = 0; et < 4; ++et) acco[et] = (f32x4){0.f,0.f,0.f,0.f};

    int jtmax = (m0 + 15) >> 6;
    for (int jt = 0; jt <= jtmax; ++jt) {
        int j0 = jt*64;
        for (int ct = 0; ct < 4; ++ct) {
            const short* krow = (const short*)Kb + ((size_t)h*SEQ + j0 + ct*16 + n)*HD + g*8;
            bf16x8 kb0 = *(const bf16x8*)krow;
            bf16x8 kb1 = *(const bf16x8*)(krow + 32);
            f32x4 sacc = {0.f,0.f,0.f,0.f};
            sacc = __builtin_amdgcn_mfma_f32_16x16x32_bf16(qa0, kb0, sacc, 0, 0, 0);
            sacc = __builtin_amdgcn_mfma_f32_16x16x32_bf16(qa1, kb1, sacc, 0, 0, 0);
            int j = j0 + ct*16 + n;
            float ej = es[j], sj = si[j];
            int chunk = ct*2 + (n>>3), e = n&7;
            for (int r = 0; r < 4; ++r) {
                int m = m0 + g*4 + r;
                float w = (j <= m) ? (A_[r]*ej + B_[r]*sj + G_[r]) : 0.f;
                int ml = g*4 + r;
                Pw[ml*64 + (chunk ^ (ml&7))*8 + e] = f2bs(w * sacc[r]);
            }
        }
        const short* vb = (const short*)Vt + (size_t)h*HD*SEQ;
        for (int et = 0; et < 4; ++et) {
            for (int sub = 0; sub < 2; ++sub) {
                int q = sub*4 + g;
                bf16x8 pa = *(const bf16x8*)(&Pw[n*64 + (q ^ (n&7))*8]);
                bf16x8 vfr = *(const bf16x8*)(vb + (size_t)(et*16 + n)*SEQ + j0 + sub*32 + g*8);
                acco[et] = __builtin_amdgcn_mfma_f32_16x16x32_bf16(pa, vfr, acco[et], 0, 0, 0);
            }
        }
    }
    // fused LayerNorm over head dim (row m = 16 lanes sharing g; 4 regs x 4 et)
    for (int r = 0; r < 4; ++r) {
        float x0 = acco[0][r], x1 = acco[1][r], x2 = acco[2][r], x3 = acco[3][r];
        float sm = x0 + x1 + x2 + x3;
        float sq = x0*x0 + x1*x1 + x2*x2 + x3*x3;
        for (int off = 1; off < 16; off <<= 1) {
            sm += __shfl_xor(sm, off);
            sq += __shfl_xor(sq, off);
        }
        float mu = sm * (1.f/64.f);
        float var = fmaxf(sq * (1.f/64.f) - mu*mu, 0.f);
        float invs = rsqrtf(var + 1e-5f);
        int m = m0 + g*4 + r;
        __hip_bfloat16* orow = opre + (size_t)m*DIM + h*HD;
        for (int et = 0; et < 4; ++et)
            orow[et*16 + n] = __float2bfloat16((acco[et][r] - mu) * invs);
    }
}

// ---------------- K5: output projection, same LDS-tiled GEMM, f32 out ----------
__global__ __launch_bounds__(256, 2) void k_oproj(const __hip_bfloat16* __restrict__ A,
    const float* __restrict__ Wo, float* __restrict__ out)
{
    int rt = blockIdx.x, ct = blockIdx.y;
    __shared__ short As[128*64], Bs[128*64];
    int tid = threadIdx.x;
    int wv = tid>>6, lane = tid&63, g = lane>>4, n = lane&15;
    int wm = wv>>1, wn = wv&1;
    int sch = tid & 7, srow = tid >> 3;
    f32x4 acc[4][4];
    for (int i=0;i<4;++i) for (int j=0;j<4;++j) acc[i][j] = (f32x4){0,0,0,0};

    for (int k0 = 0; k0 < DIM; k0 += 64) {
        for (int p = 0; p < 4; ++p) {
            int r = p*32 + srow;
            bf16x8 va = *(const bf16x8*)((const short*)A + (size_t)(rt*128 + r)*DIM + k0 + sch*8);
            *(bf16x8*)(&As[(r*8 + (sch ^ (r&7)))*8]) = va;
            bf16x8 vbv = cvt8(Wo + (size_t)(ct*128 + r)*DIM + k0 + sch*8);
            *(bf16x8*)(&Bs[(r*8 + (sch ^ (r&7)))*8]) = vbv;
        }
        __syncthreads();
        for (int ks = 0; ks < 2; ++ks) {
            bf16x8 af[4], bfr[4];
            int q = ks*4 + g;
            for (int i=0;i<4;++i) {
                int row = wm*64 + i*16 + n;
                af[i] = *(const bf16x8*)(&As[(row*8 + (q ^ (n&7)))*8]);
            }
            for (int j=0;j<4;++j) {
                int row = wn*64 + j*16 + n;
                bfr[j] = *(const bf16x8*)(&Bs[(row*8 + (q ^ (n&7)))*8]);
            }
            for (int i=0;i<4;++i)
                for (int j=0;j<4;++j)
                    acc[i][j] = __builtin_amdgcn_mfma_f32_16x16x32_bf16(af[i], bfr[j], acc[i][j], 0,0,0);
        }
        __syncthreads();
    }
    for (int i=0;i<4;++i) for (int j=0;j<4;++j) for (int r=0;r<4;++r) {
        int row = rt*128 + wm*64 + i*16 + g*4 + r;
        int col = ct*128 + wn*64 + j*16 + n;
        out[(size_t)row*DIM + col] = acc[i][j][r];
    }
}

extern "C" void kernel_launch(void* const* d_in, const int* in_sizes, int n_in,
                              void* d_out, int out_size, void* d_ws, size_t ws_size,
                              hipStream_t stream) {
    const float* X   = (const float*)d_in[0];
    const float* Wq  = (const float*)d_in[1];
    const float* Wk  = (const float*)d_in[2];
    const float* Wv  = (const float*)d_in[3];
    const float* Wu  = (const float*)d_in[4];
    const float* Wg  = (const float*)d_in[5];
    const float* Wo  = (const float*)d_in[6];
    const float* pmu = (const float*)d_in[7];
    const float* plt = (const float*)d_in[8];

    char* w = (char*)d_ws;
    __hip_bfloat16* Qb   = (__hip_bfloat16*)(w + 0);
    __hip_bfloat16* Kb   = (__hip_bfloat16*)(w + 1572864);
    __hip_bfloat16* Vt   = (__hip_bfloat16*)(w + 3145728);
    __hip_bfloat16* opre = (__hip_bfloat16*)(w + 4718592);
    float*          G    = (float*)(w + 6291456);
    float*          si_  = (float*)(w + 6438912);
    float*          es_  = si_ + NH*SEQ;
    float*          al_  = es_ + NH*SEQ;
    float*          be_  = al_ + NH*SEQ;
    float*          ga_  = be_ + NH*SEQ;
    __hip_bfloat16* Ub   = (__hip_bfloat16*)d_out;   // scratch; k_oproj overwrites last
    float*          out  = (float*)d_out;

    hipLaunchKernelGGL(k_proj5, dim3(8, 6, 5), dim3(256), 0, stream,
                       X, Wq, Wk, Wv, Wu, Wg, Qb, Kb, Vt, Ub, G);
    hipLaunchKernelGGL(k_scan, dim3(NH), dim3(1024), 0, stream,
                       Ub, G, pmu, plt, si_, es_, al_, be_, ga_);
    hipLaunchKernelGGL(k_rope, dim3(3072), dim3(256), 0, stream, Qb, Kb);
    hipLaunchKernelGGL(k_attn, dim3(16, NH), dim3(256), 0, stream,
                       Qb, Kb, Vt, si_, es_, al_, be_, ga_, opre);
    hipLaunchKernelGGL(k_oproj, dim3(8, 6), dim3(256), 0, stream,
                       opre, Wo, out);
}

// Round 5
// 213.328 us; speedup vs baseline: 1.5343x; 1.1097x over previous
//
#include <hip/hip_runtime.h>
#include <hip/hip_bf16.h>
#include <math.h>

typedef __attribute__((ext_vector_type(8))) short bf16x8;
typedef __attribute__((ext_vector_type(4))) float f32x4;

#define SEQ 1024
#define DIM 768
#define NH 12
#define HD 64

// ws layout (BYTE offsets) — total 6,684,672 B (proven size):
//   Qb   bf16 [12][1024][64]  @ 0
//   Kb   bf16 [12][1024][64]  @ 1572864
//   Vt   bf16 [768][1024]     @ 3145728   (v transposed: [h*64+e][l])
//   opre bf16 [1024][768]     @ 4718592
//   G    f32  [1024][36]      @ 6291456
//   scal f32  5*[12][1024]    @ 6438912   (si, es, al, be, ga)
// u (bf16 [12][1024][64]) borrows d_out as scratch; k_oproj overwrites it last.

__device__ __forceinline__ float wave_reduce_sum(float v) {
    for (int off = 1; off < 64; off <<= 1) v += __shfl_xor(v, off);
    return v;
}
__device__ __forceinline__ short f2bs(float x) {
    __hip_bfloat16 h = __float2bfloat16(x);
    return *reinterpret_cast<short*>(&h);
}
__device__ __forceinline__ float bs2f(short x) {
    __hip_bfloat16 h = *reinterpret_cast<__hip_bfloat16*>(&x);
    return (float)h;
}
__device__ __forceinline__ bf16x8 cvt8(const float* __restrict__ s) {
    float4 a = *(const float4*)s, b = *(const float4*)(s + 4);
    bf16x8 r;
    r[0]=f2bs(a.x); r[1]=f2bs(a.y); r[2]=f2bs(a.z); r[3]=f2bs(a.w);
    r[4]=f2bs(b.x); r[5]=f2bs(b.y); r[6]=f2bs(b.z); r[7]=f2bs(b.w);
    return r;
}

// ---------------- K1: 5 projections, LDS-tiled 128x128 GEMM, f32->bf16 staging.
// mat: 0=q 1=k 2=v(A/B swapped -> writes V^T row-contiguous) 3=u 4=gate.
// Epilogue stages C tile in LDS -> coalesced 128/256B writes; q/k epilogue also
// applies RoPE + L2-norm (2 full heads live in each 128-col tile).
__global__ __launch_bounds__(256, 2) void k_proj5(const float* __restrict__ X,
    const float* __restrict__ Wq, const float* __restrict__ Wk,
    const float* __restrict__ Wv, const float* __restrict__ Wu,
    const float* __restrict__ Wg,
    __hip_bfloat16* __restrict__ Qb, __hip_bfloat16* __restrict__ Kb,
    __hip_bfloat16* __restrict__ Vt, __hip_bfloat16* __restrict__ Ub,
    float* __restrict__ G)
{
    int rt = blockIdx.x, ct = blockIdx.y, mat = blockIdx.z;
    if (mat == 4 && ct != 0) return;
    if (mat == 2 && ct >= 6) return;      // Wv rows = 768 -> ct(=row tile) 0..5
    __shared__ short S[2][128*64];
    short* As = S[0]; short* Bs = S[1];
    int tid = threadIdx.x;
    int wv = tid>>6, lane = tid&63, g = lane>>4, n = lane&15;
    int wm = wv>>1, wn = wv&1;
    int sch = tid & 7, srow = tid >> 3;       // staging: 8 chunks x 32 rows/pass

    const float* Asrc; const float* Bsrc; int arow0, brow0, Brows;
    if (mat == 2) { Asrc = Wv; Bsrc = X; arow0 = ct*128; brow0 = rt*128; Brows = SEQ; }
    else {
        Asrc = X; arow0 = rt*128; brow0 = ct*128;
        Bsrc = (mat==0)?Wq:(mat==1)?Wk:(mat==3)?Wu:Wg;
        Brows = (mat==4) ? 36 : DIM;
    }

    f32x4 acc[4][4];
    for (int i=0;i<4;++i) for (int j=0;j<4;++j) acc[i][j] = (f32x4){0,0,0,0};

    for (int k0 = 0; k0 < DIM; k0 += 64) {
        for (int p = 0; p < 4; ++p) {
            int r = p*32 + srow;
            bf16x8 va = cvt8(Asrc + (size_t)(arow0 + r)*DIM + k0 + sch*8);
            *(bf16x8*)(&As[(r*8 + (sch ^ (r&7)))*8]) = va;
            int gr = brow0 + r; if (gr >= Brows) gr = Brows - 1;   // gate clamp
            bf16x8 vb = cvt8(Bsrc + (size_t)gr*DIM + k0 + sch*8);
            *(bf16x8*)(&Bs[(r*8 + (sch ^ (r&7)))*8]) = vb;
        }
        __syncthreads();
        for (int ks = 0; ks < 2; ++ks) {
            bf16x8 af[4], bfr[4];
            int q = ks*4 + g;
            for (int i=0;i<4;++i) {
                int row = wm*64 + i*16 + n;
                af[i] = *(const bf16x8*)(&As[(row*8 + (q ^ (n&7)))*8]);
            }
            for (int j=0;j<4;++j) {
                int row = wn*64 + j*16 + n;
                bfr[j] = *(const bf16x8*)(&Bs[(row*8 + (q ^ (n&7)))*8]);
            }
            for (int i=0;i<4;++i)
                for (int j=0;j<4;++j)
                    acc[i][j] = __builtin_amdgcn_mfma_f32_16x16x32_bf16(af[i], bfr[j], acc[i][j], 0,0,0);
        }
        __syncthreads();
    }

    // ---- gate: tiny, direct f32 writes (64B runs) ----
    if (mat == 4) {
        for (int i=0;i<4;++i) for (int j=0;j<4;++j) for (int r=0;r<4;++r) {
            int row = rt*128 + wm*64 + i*16 + g*4 + r;
            int col = wn*64 + j*16 + n;
            if (col < 36) G[(size_t)row*36 + col] = acc[i][j][r];
        }
        return;
    }

    // ---- stage C tile as bf16 [128 rows][128 cols] in LDS ----
    short* C = S[0];                      // 32 KB, reuses As+Bs
    for (int i=0;i<4;++i) for (int j=0;j<4;++j) for (int r=0;r<4;++r) {
        int lr = wm*64 + i*16 + g*4 + r;
        int lc = wn*64 + j*16 + n;
        C[lr*128 + lc] = f2bs(acc[i][j][r]);
    }
    __syncthreads();

    if (mat == 2) {
        // C[e_local][l_local]; Vt[e_global][l_global], contiguous in l.
        for (int k = 0; k < 64; ++k) {
            int u = k*4 + wv;             // 0..255
            int row = u >> 1, hsel = u & 1;
            Vt[(size_t)(ct*128 + row)*SEQ + rt*128 + hsel*64 + lane] =
                *(__hip_bfloat16*)&C[row*128 + hsel*64 + lane];
        }
    } else if (mat == 3) {
        // u -> head-major [h][l][e], contiguous in e.
        for (int k = 0; k < 64; ++k) {
            int u = k*4 + wv;
            int row = u >> 1, hsel = u & 1;
            Ub[((size_t)(2*ct + hsel)*SEQ + rt*128 + row)*HD + lane] =
                *(__hip_bfloat16*)&C[row*128 + hsel*64 + lane];
        }
    } else {
        // q/k: fused RoPE + L2 normalize, then head-major write.
        __hip_bfloat16* dst = (mat==0) ? Qb : Kb;
        int i2 = lane >> 1;
        float inv = expf((float)i2 * (-9.210340371976184f / 32.f));  // 10000^{-i2/32}
        for (int k = 0; k < 64; ++k) {
            int u = k*4 + wv;
            int row = u >> 1, hsel = u & 1;
            int l = rt*128 + row;
            float x = bs2f(C[row*128 + hsel*64 + lane]);
            float ang = (float)l * inv;
            float c = cosf(ang), s = sinf(ang);
            float p = __shfl(x, lane ^ 32);
            float rot = (lane < 32) ? -p : p;
            float y = x*c + rot*s;
            float nrm = wave_reduce_sum(y*y);
            y = y / fmaxf(sqrtf(nrm), 1e-12f);
            dst[((size_t)(2*ct + hsel)*SEQ + l)*HD + lane] = __float2bfloat16(y);
        }
    }
}

// ---------------- K2: per-head cumsum(u) -> s_i, smax, E/P scans -> alpha/beta/gamma
__global__ __launch_bounds__(1024) void k_scan(const __hip_bfloat16* __restrict__ Ub,
    const float* __restrict__ G, const float* __restrict__ pmu,
    const float* __restrict__ plt,
    float* __restrict__ si_, float* __restrict__ es_, float* __restrict__ al_,
    float* __restrict__ be_, float* __restrict__ ga_)
{
    int h = blockIdx.x;
    int tid = threadIdx.x, wv = tid >> 6, lane = tid & 63;
    __shared__ float sbuf[SEQ], ebuf[SEQ], g1b[SEQ], ghb[SEQ];
    __shared__ float stot[16][64];
    __shared__ float wmax[16];
    __shared__ float smax_s;

    float ltv = fminf(fmaxf(plt[h], -50.f), 30.f);
    float ltau = expf(ltv);
    float mu = pmu[h*HD + lane];

    const __hip_bfloat16* up = Ub + ((size_t)h*SEQ + wv*64)*HD + lane;
    float Ul = 0.f;
    for (int i = 0; i < 64; ++i) Ul += (float)up[(size_t)i*HD];
    stot[wv][lane] = Ul;
    __syncthreads();
    float pre = ltau * mu;
    for (int w2 = 0; w2 < wv; ++w2) pre += stot[w2][lane];
    float V = pre;
    for (int i = 0; i < 64; ++i) {
        float uv = (float)up[(size_t)i*HD];
        V += uv;
        int l = wv*64 + i;
        float bar = V / (ltau + (float)(l + 1));
        float p = wave_reduce_sum(uv * bar);
        if (lane == 0) sbuf[l] = -p * 0.125f;   // / sqrt(64)
    }
    __syncthreads();
    float v = sbuf[tid];
    float vm = v;
    for (int off = 1; off < 64; off <<= 1) vm = fmaxf(vm, __shfl_xor(vm, off));
    if (lane == 0) wmax[wv] = vm;
    __syncthreads();
    if (wv == 0) {
        float mm = (lane < 16) ? wmax[lane] : -1e30f;
        for (int off = 1; off < 16; off <<= 1) mm = fmaxf(mm, __shfl_xor(mm, off));
        if (lane == 0) smax_s = mm;
    }
    __syncthreads();
    float ev = expf(fminf(v - smax_s, 0.f));
    ebuf[tid] = ev;
    g1b[tid] = 1.f / (1.f + expf(-G[(size_t)tid*36 + h*3 + 0]));
    ghb[tid] = 1.f / (1.f + expf(-G[(size_t)tid*36 + h*3 + 1]));
    si_[h*SEQ + tid] = v;
    es_[h*SEQ + tid] = ev;
    __syncthreads();
    if (wv == 0) {
        int base = lane * 16;
        float se = 0.f, ss = 0.f;
        for (int i = 0; i < 16; ++i) { se += ebuf[base + i]; ss += sbuf[base + i]; }
        float pe = se, ps = ss;
        for (int off = 1; off < 64; off <<= 1) {
            float t1 = __shfl_up(pe, off), t2 = __shfl_up(ps, off);
            if (lane >= off) { pe += t1; ps += t2; }
        }
        float E = pe - se, P = ps - ss;   // exclusive prefixes
        for (int i = 0; i < 16; ++i) {
            int l = base + i;
            E += ebuf[l]; P += sbuf[l];
            float t = (float)(l + 1);
            float s1 = g1b[l], sh = ghb[l];
            float a = sh / (E + 1e-12f);
            float b = (s1 - sh) / t;
            float gm = -((b * P + sh) / t);
            al_[h*SEQ + l] = a;
            be_[h*SEQ + l] = b;
            ga_[h*SEQ + l] = gm;
        }
    }
}

// ---------------- K4: causal weighted linear attention + LayerNorm -------------
// 4-way j-split: all 4 waves work the SAME 16-row q-tile (jt strided by wave),
// partial O accumulators combined through LDS, then per-row LayerNorm.
__global__ __launch_bounds__(256) void k_attn(const __hip_bfloat16* __restrict__ Qb,
    const __hip_bfloat16* __restrict__ Kb, const __hip_bfloat16* __restrict__ Vt,
    const float* __restrict__ si_, const float* __restrict__ es_,
    const float* __restrict__ al_, const float* __restrict__ be_,
    const float* __restrict__ ga_, __hip_bfloat16* __restrict__ opre)
{
    int t = blockIdx.x, h = blockIdx.y;   // q-tile 0..63
    int wv = threadIdx.x >> 6, lane = threadIdx.x & 63;
    int g = lane >> 4, n = lane & 15;
    __shared__ short P[4][16*64];
    __shared__ float Op[4][16][64];
    short* Pw = P[wv];
    int m0 = t*16;
    const short* qrow = (const short*)Qb + ((size_t)h*SEQ + m0 + n)*HD + g*8;
    bf16x8 qa0 = *(const bf16x8*)qrow;
    bf16x8 qa1 = *(const bf16x8*)(qrow + 32);
    const float* al = al_ + h*SEQ;
    const float* be = be_ + h*SEQ;
    const float* ga = ga_ + h*SEQ;
    const float* es = es_ + h*SEQ;
    const float* si = si_ + h*SEQ;
    float A_[4], B_[4], G_[4];
    for (int r = 0; r < 4; ++r) {
        int m = m0 + g*4 + r;
        A_[r] = al[m]; B_[r] = be[m]; G_[r] = ga[m];
    }
    f32x4 acco[4];
    for (int et = 0; et < 4; ++et) acco[et] = (f32x4){0.f,0.f,0.f,0.f};

    int jtmax = t >> 2;
    for (int jt = wv; jt <= jtmax; jt += 4) {
        int j0 = jt*64;
        for (int ct = 0; ct < 4; ++ct) {
            const short* krow = (const short*)Kb + ((size_t)h*SEQ + j0 + ct*16 + n)*HD + g*8;
            bf16x8 kb0 = *(const bf16x8*)krow;
            bf16x8 kb1 = *(const bf16x8*)(krow + 32);
            f32x4 sacc = {0.f,0.f,0.f,0.f};
            sacc = __builtin_amdgcn_mfma_f32_16x16x32_bf16(qa0, kb0, sacc, 0, 0, 0);
            sacc = __builtin_amdgcn_mfma_f32_16x16x32_bf16(qa1, kb1, sacc, 0, 0, 0);
            int j = j0 + ct*16 + n;
            float ej = es[j], sj = si[j];
            int chunk = ct*2 + (n>>3), e = n&7;
            for (int r = 0; r < 4; ++r) {
                int m = m0 + g*4 + r;
                float w = (j <= m) ? (A_[r]*ej + B_[r]*sj + G_[r]) : 0.f;
                int ml = g*4 + r;
                Pw[ml*64 + (chunk ^ (ml&7))*8 + e] = f2bs(w * sacc[r]);
            }
        }
        const short* vb = (const short*)Vt + (size_t)h*HD*SEQ;
        for (int et = 0; et < 4; ++et) {
            for (int sub = 0; sub < 2; ++sub) {
                int q = sub*4 + g;
                bf16x8 pa = *(const bf16x8*)(&Pw[n*64 + (q ^ (n&7))*8]);
                bf16x8 vfr = *(const bf16x8*)(vb + (size_t)(et*16 + n)*SEQ + j0 + sub*32 + g*8);
                acco[et] = __builtin_amdgcn_mfma_f32_16x16x32_bf16(pa, vfr, acco[et], 0, 0, 0);
            }
        }
    }
    // stage partials (C-layout: col = lane&15, row = g*4 + r)
    for (int et = 0; et < 4; ++et)
        for (int r = 0; r < 4; ++r)
            Op[wv][g*4 + r][et*16 + n] = acco[et][r];
    __syncthreads();
    // combine + fused LayerNorm; wave wv handles rows wv*4..wv*4+3, lane = e
    for (int rr = 0; rr < 4; ++rr) {
        int row = wv*4 + rr;
        float v = Op[0][row][lane] + Op[1][row][lane] + Op[2][row][lane] + Op[3][row][lane];
        float sm = wave_reduce_sum(v);
        float sq = wave_reduce_sum(v*v);
        float mu = sm * (1.f/64.f);
        float var = fmaxf(sq * (1.f/64.f) - mu*mu, 0.f);
        float invs = rsqrtf(var + 1e-5f);
        opre[(size_t)(m0 + row)*DIM + h*HD + lane] = __float2bfloat16((v - mu) * invs);
    }
}

// ---------------- K5: output projection, LDS-tiled GEMM, f32 out ----------
__global__ __launch_bounds__(256, 2) void k_oproj(const __hip_bfloat16* __restrict__ A,
    const float* __restrict__ Wo, float* __restrict__ out)
{
    int rt = blockIdx.x, ct = blockIdx.y;
    __shared__ short As[128*64], Bs[128*64];
    int tid = threadIdx.x;
    int wv = tid>>6, lane = tid&63, g = lane>>4, n = lane&15;
    int wm = wv>>1, wn = wv&1;
    int sch = tid & 7, srow = tid >> 3;
    f32x4 acc[4][4];
    for (int i=0;i<4;++i) for (int j=0;j<4;++j) acc[i][j] = (f32x4){0,0,0,0};

    for (int k0 = 0; k0 < DIM; k0 += 64) {
        for (int p = 0; p < 4; ++p) {
            int r = p*32 + srow;
            bf16x8 va = *(const bf16x8*)((const short*)A + (size_t)(rt*128 + r)*DIM + k0 + sch*8);
            *(bf16x8*)(&As[(r*8 + (sch ^ (r&7)))*8]) = va;
            bf16x8 vbv = cvt8(Wo + (size_t)(ct*128 + r)*DIM + k0 + sch*8);
            *(bf16x8*)(&Bs[(r*8 + (sch ^ (r&7)))*8]) = vbv;
        }
        __syncthreads();
        for (int ks = 0; ks < 2; ++ks) {
            bf16x8 af[4], bfr[4];
            int q = ks*4 + g;
            for (int i=0;i<4;++i) {
                int row = wm*64 + i*16 + n;
                af[i] = *(const bf16x8*)(&As[(row*8 + (q ^ (n&7)))*8]);
            }
            for (int j=0;j<4;++j) {
                int row = wn*64 + j*16 + n;
                bfr[j] = *(const bf16x8*)(&Bs[(row*8 + (q ^ (n&7)))*8]);
            }
            for (int i=0;i<4;++i)
                for (int j=0;j<4;++j)
                    acc[i][j] = __builtin_amdgcn_mfma_f32_16x16x32_bf16(af[i], bfr[j], acc[i][j], 0,0,0);
        }
        __syncthreads();
    }
    for (int i=0;i<4;++i) for (int j=0;j<4;++j) for (int r=0;r<4;++r) {
        int row = rt*128 + wm*64 + i*16 + g*4 + r;
        int col = ct*128 + wn*64 + j*16 + n;
        out[(size_t)row*DIM + col] = acc[i][j][r];
    }
}

extern "C" void kernel_launch(void* const* d_in, const int* in_sizes, int n_in,
                              void* d_out, int out_size, void* d_ws, size_t ws_size,
                              hipStream_t stream) {
    const float* X   = (const float*)d_in[0];
    const float* Wq  = (const float*)d_in[1];
    const float* Wk  = (const float*)d_in[2];
    const float* Wv  = (const float*)d_in[3];
    const float* Wu  = (const float*)d_in[4];
    const float* Wg  = (const float*)d_in[5];
    const float* Wo  = (const float*)d_in[6];
    const float* pmu = (const float*)d_in[7];
    const float* plt = (const float*)d_in[8];

    char* w = (char*)d_ws;
    __hip_bfloat16* Qb   = (__hip_bfloat16*)(w + 0);
    __hip_bfloat16* Kb   = (__hip_bfloat16*)(w + 1572864);
    __hip_bfloat16* Vt   = (__hip_bfloat16*)(w + 3145728);
    __hip_bfloat16* opre = (__hip_bfloat16*)(w + 4718592);
    float*          G    = (float*)(w + 6291456);
    float*          si_  = (float*)(w + 6438912);
    float*          es_  = si_ + NH*SEQ;
    float*          al_  = es_ + NH*SEQ;
    float*          be_  = al_ + NH*SEQ;
    float*          ga_  = be_ + NH*SEQ;
    __hip_bfloat16* Ub   = (__hip_bfloat16*)d_out;   // scratch; k_oproj overwrites last
    float*          out  = (float*)d_out;

    hipLaunchKernelGGL(k_proj5, dim3(8, 6, 5), dim3(256), 0, stream,
                       X, Wq, Wk, Wv, Wu, Wg, Qb, Kb, Vt, Ub, G);
    hipLaunchKernelGGL(k_scan, dim3(NH), dim3(1024), 0, stream,
                       Ub, G, pmu, plt, si_, es_, al_, be_, ga_);
    hipLaunchKernelGGL(k_attn, dim3(64, NH), dim3(256), 0, stream,
                       Qb, Kb, Vt, si_, es_, al_, be_, ga_, opre);
    hipLaunchKernelGGL(k_oproj, dim3(8, 6), dim3(256), 0, stream,
                       opre, Wo, out);
}

// Round 7
// 176.465 us; speedup vs baseline: 1.8548x; 1.2089x over previous
//
#include <hip/hip_runtime.h>
#include <hip/hip_bf16.h>
#include <math.h>

typedef __attribute__((ext_vector_type(8))) short bf16x8;
typedef __attribute__((ext_vector_type(4))) float f32x4;

#define SEQ 1024
#define DIM 768
#define NH 12
#define HD 64

// ws layout (BYTE offsets) — total 6,684,672 B (proven size):
//   Qb   bf16 [12][1024][64]  @ 0
//   Kb   bf16 [12][1024][64]  @ 1572864
//   Vt   bf16 [768][1024]     @ 3145728   (v transposed: [h*64+e][l])
//   opre bf16 [1024][768]     @ 4718592
//   G    f32  [1024][36]      @ 6291456
//   scal f32  5*[12][1024]    @ 6438912   (si, es, al, be, ga)
// u (bf16 [12][1024][64]) borrows d_out as scratch; k_oproj overwrites it last.

__device__ __forceinline__ float wave_reduce_sum(float v) {
    for (int off = 1; off < 64; off <<= 1) v += __shfl_xor(v, off);
    return v;
}
__device__ __forceinline__ short f2bs(float x) {
    __hip_bfloat16 h = __float2bfloat16(x);
    return *reinterpret_cast<short*>(&h);
}
__device__ __forceinline__ float bs2f(short x) {
    __hip_bfloat16 h = *reinterpret_cast<__hip_bfloat16*>(&x);
    return (float)h;
}
__device__ __forceinline__ bf16x8 cvt8r(const float4& a, const float4& b) {
    bf16x8 r;
    r[0]=f2bs(a.x); r[1]=f2bs(a.y); r[2]=f2bs(a.z); r[3]=f2bs(a.w);
    r[4]=f2bs(b.x); r[5]=f2bs(b.y); r[6]=f2bs(b.z); r[7]=f2bs(b.w);
    return r;
}

// ---------------- K1: 5 projections, 64x128 double-buffered LDS GEMM ----------
// mat: 0=q 1=k 2=v(A/B swapped -> V^T row-contiguous) 3=u 4=gate.
// Pipelined staging: raw float4 prefetch -> MFMA phase -> cvt+LDS commit.
// Epilogue via LDS C-staging; q/k fuse RoPE + L2-norm.
// NOTE: no LDS pointer arrays (addrspacecast static-init bug) — compute bases.
__global__ __launch_bounds__(256, 3) void k_proj5(const float* __restrict__ X,
    const float* __restrict__ Wq, const float* __restrict__ Wk,
    const float* __restrict__ Wv, const float* __restrict__ Wu,
    const float* __restrict__ Wg,
    __hip_bfloat16* __restrict__ Qb, __hip_bfloat16* __restrict__ Kb,
    __hip_bfloat16* __restrict__ Vt, __hip_bfloat16* __restrict__ Ub,
    float* __restrict__ G)
{
    int rt = blockIdx.x, ct = blockIdx.y, mat = blockIdx.z;
    if (mat == 4 && ct != 0) return;
    if (mat == 2 && rt >= 12) return;
    if ((mat == 0 || mat == 1 || mat == 3) && ct >= 6) return;

    __shared__ short lds[24576];                       // 48 KB
    // layout: A buffers at 0 / 4096 (64x64), B buffers at 8192 / 16384 (128x64)

    int tid = threadIdx.x;
    int wv = tid>>6, lane = tid&63, g = lane>>4, n = lane&15;
    int wn = wv;                                       // wave owns 32 cols of 128
    int sch = tid & 7, srow = tid >> 3;                // 8 chunks x 32 rows

    const float* Asrc; const float* Bsrc; int arow0, brow0, Brows;
    if (mat == 2) { Asrc = Wv; Bsrc = X; arow0 = rt*64; brow0 = ct*128; Brows = SEQ; }
    else {
        Asrc = X; arow0 = rt*64; brow0 = ct*128;
        Bsrc = (mat==0)?Wq:(mat==1)?Wk:(mat==3)?Wu:Wg;
        Brows = (mat==4) ? 36 : DIM;
    }

    float4 ra[2][2], rb[4][2];
    auto prefetch = [&](int k0) {
        for (int p = 0; p < 2; ++p) {
            const float* s = Asrc + (size_t)(arow0 + srow + p*32)*DIM + k0 + sch*8;
            ra[p][0] = *(const float4*)s; ra[p][1] = *(const float4*)(s + 4);
        }
        for (int p = 0; p < 4; ++p) {
            int gr = brow0 + srow + p*32; if (gr >= Brows) gr = Brows - 1;
            const float* s = Bsrc + (size_t)gr*DIM + k0 + sch*8;
            rb[p][0] = *(const float4*)s; rb[p][1] = *(const float4*)(s + 4);
        }
    };
    auto commit = [&](int buf) {
        short* Ab = lds + buf*4096;
        short* Bb = lds + 8192 + buf*8192;
        for (int p = 0; p < 2; ++p) {
            int r = srow + p*32;
            *(bf16x8*)(&Ab[(r*8 + (sch ^ (r&7)))*8]) = cvt8r(ra[p][0], ra[p][1]);
        }
        for (int p = 0; p < 4; ++p) {
            int r = srow + p*32;
            *(bf16x8*)(&Bb[(r*8 + (sch ^ (r&7)))*8]) = cvt8r(rb[p][0], rb[p][1]);
        }
    };

    f32x4 acc[4][2];
    for (int i=0;i<4;++i) for (int j=0;j<2;++j) acc[i][j] = (f32x4){0,0,0,0};

    prefetch(0);
    commit(0);
    for (int it = 0; it < 12; ++it) {
        __syncthreads();
        if (it < 11) prefetch((it+1)*64);
        int buf = it & 1;
        const short* Ab = lds + buf*4096;
        const short* Bb = lds + 8192 + buf*8192;
        for (int ks = 0; ks < 2; ++ks) {
            int q = ks*4 + g;
            bf16x8 af[4], bfr[2];
            for (int i=0;i<4;++i)
                af[i] = *(const bf16x8*)(&Ab[((i*16+n)*8 + (q ^ (n&7)))*8]);
            for (int j=0;j<2;++j)
                bfr[j] = *(const bf16x8*)(&Bb[((wn*32+j*16+n)*8 + (q ^ (n&7)))*8]);
            for (int i=0;i<4;++i)
                for (int j=0;j<2;++j)
                    acc[i][j] = __builtin_amdgcn_mfma_f32_16x16x32_bf16(af[i], bfr[j], acc[i][j], 0,0,0);
        }
        if (it < 11) commit(1 - buf);
    }
    __syncthreads();

    // ---- gate: tiny, direct f32 writes ----
    if (mat == 4) {
        for (int i=0;i<4;++i) for (int j=0;j<2;++j) for (int r=0;r<4;++r) {
            int row = rt*64 + i*16 + g*4 + r;
            int col = wn*32 + j*16 + n;
            if (col < 36) G[(size_t)row*36 + col] = acc[i][j][r];
        }
        return;
    }

    // ---- stage C tile bf16 [64 rows][128 cols] in LDS (reuses buffers) ----
    short* C = lds;
    for (int i=0;i<4;++i) for (int j=0;j<2;++j) for (int r=0;r<4;++r)
        C[(i*16 + g*4 + r)*128 + wn*32 + j*16 + n] = f2bs(acc[i][j][r]);
    __syncthreads();

    if (mat == 2) {
        // C[e_local][l_local] -> Vt[e][l], 256B runs via uint
        for (int k = 0; k < 16; ++k) {
            int row = k*4 + wv;
            unsigned int v = ((const unsigned int*)C)[row*64 + lane];
            ((unsigned int*)(Vt + (size_t)(rt*64 + row)*SEQ + ct*128))[lane] = v;
        }
    } else if (mat == 3) {
        for (int k = 0; k < 32; ++k) {
            int u = k*4 + wv;             // 0..127 row-head pairs
            int row = u >> 1, hsel = u & 1;
            Ub[((size_t)(2*ct + hsel)*SEQ + rt*64 + row)*HD + lane] =
                *(__hip_bfloat16*)&C[row*128 + hsel*64 + lane];
        }
    } else {
        // q/k: fused RoPE + L2 normalize, head-major write
        __hip_bfloat16* dst = (mat==0) ? Qb : Kb;
        int i2 = lane >> 1;
        float inv = expf((float)i2 * (-9.210340371976184f / 32.f));  // 10000^{-i2/32}
        for (int k = 0; k < 32; ++k) {
            int u = k*4 + wv;
            int row = u >> 1, hsel = u & 1;
            int l = rt*64 + row;
            float x = bs2f(C[row*128 + hsel*64 + lane]);
            float ang = (float)l * inv;
            float c = cosf(ang), s = sinf(ang);
            float p = __shfl(x, lane ^ 32);
            float rot = (lane < 32) ? -p : p;
            float y = x*c + rot*s;
            float nrm = wave_reduce_sum(y*y);
            y = y / fmaxf(sqrtf(nrm), 1e-12f);
            dst[((size_t)(2*ct + hsel)*SEQ + l)*HD + lane] = __float2bfloat16(y);
        }
    }
}

// ---------------- K2: per-head cumsum(u) -> s_i, smax, E/P scans -> alpha/beta/gamma
__global__ __launch_bounds__(1024) void k_scan(const __hip_bfloat16* __restrict__ Ub,
    const float* __restrict__ G, const float* __restrict__ pmu,
    const float* __restrict__ plt,
    float* __restrict__ si_, float* __restrict__ es_, float* __restrict__ al_,
    float* __restrict__ be_, float* __restrict__ ga_)
{
    int h = blockIdx.x;
    int tid = threadIdx.x, wv = tid >> 6, lane = tid & 63;
    __shared__ float sbuf[SEQ], ebuf[SEQ], g1b[SEQ], ghb[SEQ];
    __shared__ float stot[16][64];
    __shared__ float wmax[16];
    __shared__ float smax_s;

    float ltv = fminf(fmaxf(plt[h], -50.f), 30.f);
    float ltau = expf(ltv);
    float mu = pmu[h*HD + lane];

    const __hip_bfloat16* up = Ub + ((size_t)h*SEQ + wv*64)*HD + lane;
    float Ul = 0.f;
    for (int i = 0; i < 64; ++i) Ul += (float)up[(size_t)i*HD];
    stot[wv][lane] = Ul;
    __syncthreads();
    float pre = ltau * mu;
    for (int w2 = 0; w2 < wv; ++w2) pre += stot[w2][lane];
    float V = pre;
    for (int i = 0; i < 64; ++i) {
        float uv = (float)up[(size_t)i*HD];
        V += uv;
        int l = wv*64 + i;
        float bar = V / (ltau + (float)(l + 1));
        float p = wave_reduce_sum(uv * bar);
        if (lane == 0) sbuf[l] = -p * 0.125f;   // / sqrt(64)
    }
    __syncthreads();
    float v = sbuf[tid];
    float vm = v;
    for (int off = 1; off < 64; off <<= 1) vm = fmaxf(vm, __shfl_xor(vm, off));
    if (lane == 0) wmax[wv] = vm;
    __syncthreads();
    if (wv == 0) {
        float mm = (lane < 16) ? wmax[lane] : -1e30f;
        for (int off = 1; off < 16; off <<= 1) mm = fmaxf(mm, __shfl_xor(mm, off));
        if (lane == 0) smax_s = mm;
    }
    __syncthreads();
    float ev = expf(fminf(v - smax_s, 0.f));
    ebuf[tid] = ev;
    g1b[tid] = 1.f / (1.f + expf(-G[(size_t)tid*36 + h*3 + 0]));
    ghb[tid] = 1.f / (1.f + expf(-G[(size_t)tid*36 + h*3 + 1]));
    si_[h*SEQ + tid] = v;
    es_[h*SEQ + tid] = ev;
    __syncthreads();
    if (wv == 0) {
        int base = lane * 16;
        float se = 0.f, ss = 0.f;
        for (int i = 0; i < 16; ++i) { se += ebuf[base + i]; ss += sbuf[base + i]; }
        float pe = se, ps = ss;
        for (int off = 1; off < 64; off <<= 1) {
            float t1 = __shfl_up(pe, off), t2 = __shfl_up(ps, off);
            if (lane >= off) { pe += t1; ps += t2; }
        }
        float E = pe - se, P = ps - ss;   // exclusive prefixes
        for (int i = 0; i < 16; ++i) {
            int l = base + i;
            E += ebuf[l]; P += sbuf[l];
            float t = (float)(l + 1);
            float s1 = g1b[l], sh = ghb[l];
            float a = sh / (E + 1e-12f);
            float b = (s1 - sh) / t;
            float gm = -((b * P + sh) / t);
            al_[h*SEQ + l] = a;
            be_[h*SEQ + l] = b;
            ga_[h*SEQ + l] = gm;
        }
    }
}

// ---------------- K4: causal weighted linear attention + LayerNorm -------------
// 4-way j-split: all 4 waves work the SAME 16-row q-tile (jt strided by wave),
// partial O accumulators combined through LDS, then per-row LayerNorm.
__global__ __launch_bounds__(256) void k_attn(const __hip_bfloat16* __restrict__ Qb,
    const __hip_bfloat16* __restrict__ Kb, const __hip_bfloat16* __restrict__ Vt,
    const float* __restrict__ si_, const float* __restrict__ es_,
    const float* __restrict__ al_, const float* __restrict__ be_,
    const float* __restrict__ ga_, __hip_bfloat16* __restrict__ opre)
{
    int t = blockIdx.x, h = blockIdx.y;   // q-tile 0..63
    int wv = threadIdx.x >> 6, lane = threadIdx.x & 63;
    int g = lane >> 4, n = lane & 15;
    __shared__ short P[4][16*64];
    __shared__ float Op[4][16][64];
    short* Pw = P[wv];
    int m0 = t*16;
    const short* qrow = (const short*)Qb + ((size_t)h*SEQ + m0 + n)*HD + g*8;
    bf16x8 qa0 = *(const bf16x8*)qrow;
    bf16x8 qa1 = *(const bf16x8*)(qrow + 32);
    const float* al = al_ + h*SEQ;
    const float* be = be_ + h*SEQ;
    const float* ga = ga_ + h*SEQ;
    const float* es = es_ + h*SEQ;
    const float* si = si_ + h*SEQ;
    float A_[4], B_[4], G_[4];
    for (int r = 0; r < 4; ++r) {
        int m = m0 + g*4 + r;
        A_[r] = al[m]; B_[r] = be[m]; G_[r] = ga[m];
    }
    f32x4 acco[4];
    for (int et = 0; et < 4; ++et) acco[et] = (f32x4){0.f,0.f,0.f,0.f};

    int jtmax = t >> 2;
    for (int jt = wv; jt <= jtmax; jt += 4) {
        int j0 = jt*64;
        for (int ct = 0; ct < 4; ++ct) {
            const short* krow = (const short*)Kb + ((size_t)h*SEQ + j0 + ct*16 + n)*HD + g*8;
            bf16x8 kb0 = *(const bf16x8*)krow;
            bf16x8 kb1 = *(const bf16x8*)(krow + 32);
            f32x4 sacc = {0.f,0.f,0.f,0.f};
            sacc = __builtin_amdgcn_mfma_f32_16x16x32_bf16(qa0, kb0, sacc, 0, 0, 0);
            sacc = __builtin_amdgcn_mfma_f32_16x16x32_bf16(qa1, kb1, sacc, 0, 0, 0);
            int j = j0 + ct*16 + n;
            float ej = es[j], sj = si[j];
            int chunk = ct*2 + (n>>3), e = n&7;
            for (int r = 0; r < 4; ++r) {
                int m = m0 + g*4 + r;
                float w = (j <= m) ? (A_[r]*ej + B_[r]*sj + G_[r]) : 0.f;
                int ml = g*4 + r;
                Pw[ml*64 + (chunk ^ (ml&7))*8 + e] = f2bs(w * sacc[r]);
            }
        }
        const short* vb = (const short*)Vt + (size_t)h*HD*SEQ;
        for (int et = 0; et < 4; ++et) {
            for (int sub = 0; sub < 2; ++sub) {
                int q = sub*4 + g;
                bf16x8 pa = *(const bf16x8*)(&Pw[n*64 + (q ^ (n&7))*8]);
                bf16x8 vfr = *(const bf16x8*)(vb + (size_t)(et*16 + n)*SEQ + j0 + sub*32 + g*8);
                acco[et] = __builtin_amdgcn_mfma_f32_16x16x32_bf16(pa, vfr, acco[et], 0, 0, 0);
            }
        }
    }
    // stage partials (C-layout: col = lane&15, row = g*4 + r)
    for (int et = 0; et < 4; ++et)
        for (int r = 0; r < 4; ++r)
            Op[wv][g*4 + r][et*16 + n] = acco[et][r];
    __syncthreads();
    // combine + fused LayerNorm; wave wv handles rows wv*4..wv*4+3, lane = e
    for (int rr = 0; rr < 4; ++rr) {
        int row = wv*4 + rr;
        float v = Op[0][row][lane] + Op[1][row][lane] + Op[2][row][lane] + Op[3][row][lane];
        float sm = wave_reduce_sum(v);
        float sq = wave_reduce_sum(v*v);
        float mu = sm * (1.f/64.f);
        float var = fmaxf(sq * (1.f/64.f) - mu*mu, 0.f);
        float invs = rsqrtf(var + 1e-5f);
        opre[(size_t)(m0 + row)*DIM + h*HD + lane] = __float2bfloat16((v - mu) * invs);
    }
}

// ---------------- K5: output projection, 64x64 double-buffered GEMM, f32 out ---
__global__ __launch_bounds__(256, 4) void k_oproj(const __hip_bfloat16* __restrict__ A,
    const float* __restrict__ Wo, float* __restrict__ out)
{
    int rt = blockIdx.x, ct = blockIdx.y;
    __shared__ short lds[16384];                      // 32 KB
    // A buffers at 0 / 4096, B buffers at 8192 / 12288 (64x64 bf16 each)

    int tid = threadIdx.x;
    int wv = tid>>6, lane = tid&63, g = lane>>4, n = lane&15;
    int wm = wv>>1, wn = wv&1;
    int sch = tid & 7, srow = tid >> 3;

    bf16x8 raA[2]; float4 rbB[2][2];
    auto prefetch = [&](int k0) {
        for (int p = 0; p < 2; ++p) {
            raA[p] = *(const bf16x8*)((const short*)A + (size_t)(rt*64 + srow + p*32)*DIM + k0 + sch*8);
            const float* s = Wo + (size_t)(ct*64 + srow + p*32)*DIM + k0 + sch*8;
            rbB[p][0] = *(const float4*)s; rbB[p][1] = *(const float4*)(s + 4);
        }
    };
    auto commit = [&](int buf) {
        short* Ab = lds + buf*4096;
        short* Bb = lds + 8192 + buf*4096;
        for (int p = 0; p < 2; ++p) {
            int r = srow + p*32;
            *(bf16x8*)(&Ab[(r*8 + (sch ^ (r&7)))*8]) = raA[p];
            *(bf16x8*)(&Bb[(r*8 + (sch ^ (r&7)))*8]) = cvt8r(rbB[p][0], rbB[p][1]);
        }
    };

    f32x4 acc[2][2];
    for (int i=0;i<2;++i) for (int j=0;j<2;++j) acc[i][j] = (f32x4){0,0,0,0};

    prefetch(0);
    commit(0);
    for (int it = 0; it < 12; ++it) {
        __syncthreads();
        if (it < 11) prefetch((it+1)*64);
        int buf = it & 1;
        const short* Ab = lds + buf*4096;
        const short* Bb = lds + 8192 + buf*4096;
        for (int ks = 0; ks < 2; ++ks) {
            int q = ks*4 + g;
            bf16x8 af[2], bfr[2];
            for (int i=0;i<2;++i)
                af[i] = *(const bf16x8*)(&Ab[((wm*32+i*16+n)*8 + (q ^ (n&7)))*8]);
            for (int j=0;j<2;++j)
                bfr[j] = *(const bf16x8*)(&Bb[((wn*32+j*16+n)*8 + (q ^ (n&7)))*8]);
            for (int i=0;i<2;++i)
                for (int j=0;j<2;++j)
                    acc[i][j] = __builtin_amdgcn_mfma_f32_16x16x32_bf16(af[i], bfr[j], acc[i][j], 0,0,0);
        }
        if (it < 11) commit(1 - buf);
    }
    for (int i=0;i<2;++i) for (int j=0;j<2;++j) for (int r=0;r<4;++r) {
        int row = rt*64 + wm*32 + i*16 + g*4 + r;
        int col = ct*64 + wn*32 + j*16 + n;
        out[(size_t)row*DIM + col] = acc[i][j][r];
    }
}

extern "C" void kernel_launch(void* const* d_in, const int* in_sizes, int n_in,
                              void* d_out, int out_size, void* d_ws, size_t ws_size,
                              hipStream_t stream) {
    const float* X   = (const float*)d_in[0];
    const float* Wq  = (const float*)d_in[1];
    const float* Wk  = (const float*)d_in[2];
    const float* Wv  = (const float*)d_in[3];
    const float* Wu  = (const float*)d_in[4];
    const float* Wg  = (const float*)d_in[5];
    const float* Wo  = (const float*)d_in[6];
    const float* pmu = (const float*)d_in[7];
    const float* plt = (const float*)d_in[8];

    char* w = (char*)d_ws;
    __hip_bfloat16* Qb   = (__hip_bfloat16*)(w + 0);
    __hip_bfloat16* Kb   = (__hip_bfloat16*)(w + 1572864);
    __hip_bfloat16* Vt   = (__hip_bfloat16*)(w + 3145728);
    __hip_bfloat16* opre = (__hip_bfloat16*)(w + 4718592);
    float*          G    = (float*)(w + 6291456);
    float*          si_  = (float*)(w + 6438912);
    float*          es_  = si_ + NH*SEQ;
    float*          al_  = es_ + NH*SEQ;
    float*          be_  = al_ + NH*SEQ;
    float*          ga_  = be_ + NH*SEQ;
    __hip_bfloat16* Ub   = (__hip_bfloat16*)d_out;   // scratch; k_oproj overwrites last
    float*          out  = (float*)d_out;

    hipLaunchKernelGGL(k_proj5, dim3(16, 8, 5), dim3(256), 0, stream,
                       X, Wq, Wk, Wv, Wu, Wg, Qb, Kb, Vt, Ub, G);
    hipLaunchKernelGGL(k_scan, dim3(NH), dim3(1024), 0, stream,
                       Ub, G, pmu, plt, si_, es_, al_, be_, ga_);
    hipLaunchKernelGGL(k_attn, dim3(64, NH), dim3(256), 0, stream,
                       Qb, Kb, Vt, si_, es_, al_, be_, ga_, opre);
    hipLaunchKernelGGL(k_oproj, dim3(16, 12), dim3(256), 0, stream,
                       opre, Wo, out);
}

// Round 8
// 172.886 us; speedup vs baseline: 1.8932x; 1.0207x over previous
//
#include <hip/hip_runtime.h>
#include <hip/hip_bf16.h>
#include <math.h>

typedef __attribute__((ext_vector_type(8))) short bf16x8;
typedef __attribute__((ext_vector_type(4))) float f32x4;

#define SEQ 1024
#define DIM 768
#define NH 12
#define HD 64

// ws layout (BYTE offsets):
//   Qb   bf16 [12][1024][64]  @ 0
//   Kb   bf16 [12][1024][64]  @ 1572864
//   Vt   bf16 [768][1024]     @ 3145728   (v transposed: [h*64+e][l])
//   opre bf16 [1024][768]     @ 4718592
//   G    f32  [1024][36]      @ 6291456
//   scal f32  5*[12][1024]    @ 6438912   (si, es, al, be, ga)
//   Xb   bf16 [1024][768]     @ 6684672   (pre-cast inputs for DMA staging)
//   Wqb  bf16 [768][768]      @ 8257536
//   Wkb  bf16 [768][768]      @ 9437184
//   Wvb  bf16 [768][768]      @ 10616832
//   Wub  bf16 [768][768]      @ 11796480
//   Wgb  bf16 [36][768]       @ 12976128
//   Wob  bf16 [768][768]      @ 13031424   (end ~14.2 MB; ws alloc is 256 MiB)
// u (bf16 [12][1024][64]) borrows d_out as scratch; k_oproj overwrites it last.

__device__ __forceinline__ float wave_reduce_sum(float v) {
    for (int off = 1; off < 64; off <<= 1) v += __shfl_xor(v, off);
    return v;
}
__device__ __forceinline__ short f2bs(float x) {
    __hip_bfloat16 h = __float2bfloat16(x);
    return *reinterpret_cast<short*>(&h);
}
__device__ __forceinline__ float bs2f(short x) {
    __hip_bfloat16 h = *reinterpret_cast<__hip_bfloat16*>(&x);
    return (float)h;
}
__device__ __forceinline__ bf16x8 cvt8r(const float4& a, const float4& b) {
    bf16x8 r;
    r[0]=f2bs(a.x); r[1]=f2bs(a.y); r[2]=f2bs(a.z); r[3]=f2bs(a.w);
    r[4]=f2bs(b.x); r[5]=f2bs(b.y); r[6]=f2bs(b.z); r[7]=f2bs(b.w);
    return r;
}

// async 16B/lane global->LDS DMA. ldsbase is the WAVE-uniform base; HW writes
// lane L's 16 bytes at ldsbase + L*16. gptr is per-lane.
__device__ __forceinline__ void async_copy16(const void* gptr, void* ldsbase, int lane) {
#if __has_builtin(__builtin_amdgcn_global_load_lds)
    __builtin_amdgcn_global_load_lds(
        (const __attribute__((address_space(1))) unsigned int*)gptr,
        (__attribute__((address_space(3))) unsigned int*)ldsbase, 16, 0, 0);
#else
    *(bf16x8*)((short*)ldsbase + lane*8) = *(const bf16x8*)gptr;
#endif
}

// ---------------- K0: pre-cast X + weights to bf16 (one pass, BW-bound) -------
__global__ __launch_bounds__(256) void k_prep(const float* __restrict__ X,
    const float* __restrict__ Wq, const float* __restrict__ Wk,
    const float* __restrict__ Wv, const float* __restrict__ Wu,
    const float* __restrict__ Wg, const float* __restrict__ Wo,
    short* __restrict__ Xb, short* __restrict__ Wqb, short* __restrict__ Wkb,
    short* __restrict__ Wvb, short* __restrict__ Wub, short* __restrict__ Wgb,
    short* __restrict__ Wob)
{
    int seg = blockIdx.y;
    const float* src; short* dst; int n8;
    switch (seg) {
        case 0: src = X;  dst = Xb;  n8 = 98304; break;
        case 1: src = Wq; dst = Wqb; n8 = 73728; break;
        case 2: src = Wk; dst = Wkb; n8 = 73728; break;
        case 3: src = Wv; dst = Wvb; n8 = 73728; break;
        case 4: src = Wu; dst = Wub; n8 = 73728; break;
        case 5: src = Wg; dst = Wgb; n8 = 3456;  break;
        default: src = Wo; dst = Wob; n8 = 73728; break;
    }
    int i = blockIdx.x*256 + threadIdx.x;
    if (i >= n8) return;
    const float* s = src + (size_t)i*8;
    *(bf16x8*)(dst + (size_t)i*8) = cvt8r(*(const float4*)s, *(const float4*)(s + 4));
}

// ---------------- K1: 5 projections, 64x128 dbuf GEMM, global_load_lds staging
// mat: 0=q 1=k 2=v(A/B swapped -> V^T row-contiguous) 3=u 4=gate.
// DMA source addresses are permuted so data lands in the XOR-swizzled layout
// (LDS dest is lane-contiguous; you permute the SOURCE, not the dest).
__global__ __launch_bounds__(256, 3) void k_proj5(const short* __restrict__ Xb,
    const short* __restrict__ Wqb, const short* __restrict__ Wkb,
    const short* __restrict__ Wvb, const short* __restrict__ Wub,
    const short* __restrict__ Wgb,
    __hip_bfloat16* __restrict__ Qb, __hip_bfloat16* __restrict__ Kb,
    __hip_bfloat16* __restrict__ Vt, __hip_bfloat16* __restrict__ Ub,
    float* __restrict__ G)
{
    int rt = blockIdx.x, ct = blockIdx.y, mat = blockIdx.z;
    if (mat == 4 && ct != 0) return;
    if (mat == 2 && rt >= 12) return;
    if ((mat == 0 || mat == 1 || mat == 3) && ct >= 6) return;

    __shared__ short lds[24576];   // A dbuf @0/4096 (64x64), B dbuf @8192/16384 (128x64)

    int tid = threadIdx.x;
    int wv = tid>>6, lane = tid&63, g = lane>>4, n = lane&15;
    int wn = wv;                                       // wave owns 32 cols of 128

    const short* Asrc; const short* Bsrc; int arow0, brow0, Brows;
    if (mat == 2) { Asrc = Wvb; Bsrc = Xb; arow0 = rt*64; brow0 = ct*128; Brows = SEQ; }
    else {
        Asrc = Xb; arow0 = rt*64; brow0 = ct*128;
        Bsrc = (mat==0)?Wqb:(mat==1)?Wkb:(mat==3)?Wub:Wgb;
        Brows = (mat==4) ? 36 : DIM;
    }

    auto dma_step = [&](int buf, int k0) {
        short* Ab = lds + buf*4096;
        short* Bb = lds + 8192 + buf*8192;
        for (int p = 0; p < 2; ++p) {                  // A: 64 rows x 8 chunks
            int sbase = p*256 + wv*64;
            int s = sbase + lane;
            int r = s >> 3, c = s & 7, cl = c ^ (r & 7);
            const short* gp = Asrc + (size_t)(arow0 + r)*DIM + k0 + cl*8;
            async_copy16(gp, Ab + sbase*8, lane);
        }
        for (int p = 0; p < 4; ++p) {                  // B: 128 rows x 8 chunks
            int sbase = p*256 + wv*64;
            int s = sbase + lane;
            int r = s >> 3, c = s & 7, cl = c ^ (r & 7);
            int gr = brow0 + r; if (gr >= Brows) gr = Brows - 1;   // gate clamp
            const short* gp = Bsrc + (size_t)gr*DIM + k0 + cl*8;
            async_copy16(gp, Bb + sbase*8, lane);
        }
    };

    f32x4 acc[4][2];
    for (int i=0;i<4;++i) for (int j=0;j<2;++j) acc[i][j] = (f32x4){0,0,0,0};

    dma_step(0, 0);
    for (int it = 0; it < 12; ++it) {
        __syncthreads();                                // drains DMA for buf it&1
        if (it < 11) dma_step(1 - (it & 1), (it + 1)*64);
        int buf = it & 1;
        const short* Ab = lds + buf*4096;
        const short* Bb = lds + 8192 + buf*8192;
        for (int ks = 0; ks < 2; ++ks) {
            int q = ks*4 + g;
            bf16x8 af[4], bfr[2];
            for (int i=0;i<4;++i)
                af[i] = *(const bf16x8*)(&Ab[((i*16+n)*8 + (q ^ (n&7)))*8]);
            for (int j=0;j<2;++j)
                bfr[j] = *(const bf16x8*)(&Bb[((wn*32+j*16+n)*8 + (q ^ (n&7)))*8]);
            for (int i=0;i<4;++i)
                for (int j=0;j<2;++j)
                    acc[i][j] = __builtin_amdgcn_mfma_f32_16x16x32_bf16(af[i], bfr[j], acc[i][j], 0,0,0);
        }
    }
    __syncthreads();

    // ---- gate: tiny, direct f32 writes ----
    if (mat == 4) {
        for (int i=0;i<4;++i) for (int j=0;j<2;++j) for (int r=0;r<4;++r) {
            int row = rt*64 + i*16 + g*4 + r;
            int col = wn*32 + j*16 + n;
            if (col < 36) G[(size_t)row*36 + col] = acc[i][j][r];
        }
        return;
    }

    // ---- stage C tile bf16 [64 rows][128 cols] in LDS (reuses A buffers) ----
    short* C = lds;
    for (int i=0;i<4;++i) for (int j=0;j<2;++j) for (int r=0;r<4;++r)
        C[(i*16 + g*4 + r)*128 + wn*32 + j*16 + n] = f2bs(acc[i][j][r]);
    __syncthreads();

    if (mat == 2) {
        // C[e_local][l_local] -> Vt[e][l], 256B runs via uint
        for (int k = 0; k < 16; ++k) {
            int row = k*4 + wv;
            unsigned int v = ((const unsigned int*)C)[row*64 + lane];
            ((unsigned int*)(Vt + (size_t)(rt*64 + row)*SEQ + ct*128))[lane] = v;
        }
    } else if (mat == 3) {
        for (int k = 0; k < 32; ++k) {
            int u = k*4 + wv;             // 0..127 row-head pairs
            int row = u >> 1, hsel = u & 1;
            Ub[((size_t)(2*ct + hsel)*SEQ + rt*64 + row)*HD + lane] =
                *(__hip_bfloat16*)&C[row*128 + hsel*64 + lane];
        }
    } else {
        // q/k: fused RoPE + L2 normalize, head-major write
        __hip_bfloat16* dst = (mat==0) ? Qb : Kb;
        int i2 = lane >> 1;
        float inv = expf((float)i2 * (-9.210340371976184f / 32.f));  // 10000^{-i2/32}
        for (int k = 0; k < 32; ++k) {
            int u = k*4 + wv;
            int row = u >> 1, hsel = u & 1;
            int l = rt*64 + row;
            float x = bs2f(C[row*128 + hsel*64 + lane]);
            float ang = (float)l * inv;
            float c = cosf(ang), s = sinf(ang);
            float p = __shfl(x, lane ^ 32);
            float rot = (lane < 32) ? -p : p;
            float y = x*c + rot*s;
            float nrm = wave_reduce_sum(y*y);
            y = y / fmaxf(sqrtf(nrm), 1e-12f);
            dst[((size_t)(2*ct + hsel)*SEQ + l)*HD + lane] = __float2bfloat16(y);
        }
    }
}

// ---------------- K2: per-head cumsum(u) -> s_i, smax, E/P scans -> alpha/beta/gamma
__global__ __launch_bounds__(1024) void k_scan(const __hip_bfloat16* __restrict__ Ub,
    const float* __restrict__ G, const float* __restrict__ pmu,
    const float* __restrict__ plt,
    float* __restrict__ si_, float* __restrict__ es_, float* __restrict__ al_,
    float* __restrict__ be_, float* __restrict__ ga_)
{
    int h = blockIdx.x;
    int tid = threadIdx.x, wv = tid >> 6, lane = tid & 63;
    __shared__ float sbuf[SEQ], ebuf[SEQ], g1b[SEQ], ghb[SEQ];
    __shared__ float stot[16][64];
    __shared__ float wmax[16];
    __shared__ float smax_s;

    float ltv = fminf(fmaxf(plt[h], -50.f), 30.f);
    float ltau = expf(ltv);
    float mu = pmu[h*HD + lane];

    const __hip_bfloat16* up = Ub + ((size_t)h*SEQ + wv*64)*HD + lane;
    float Ul = 0.f;
    for (int i = 0; i < 64; ++i) Ul += (float)up[(size_t)i*HD];
    stot[wv][lane] = Ul;
    __syncthreads();
    float pre = ltau * mu;
    for (int w2 = 0; w2 < wv; ++w2) pre += stot[w2][lane];
    float V = pre;
    for (int i = 0; i < 64; ++i) {
        float uv = (float)up[(size_t)i*HD];
        V += uv;
        int l = wv*64 + i;
        float bar = V / (ltau + (float)(l + 1));
        float p = wave_reduce_sum(uv * bar);
        if (lane == 0) sbuf[l] = -p * 0.125f;   // / sqrt(64)
    }
    __syncthreads();
    float v = sbuf[tid];
    float vm = v;
    for (int off = 1; off < 64; off <<= 1) vm = fmaxf(vm, __shfl_xor(vm, off));
    if (lane == 0) wmax[wv] = vm;
    __syncthreads();
    if (wv == 0) {
        float mm = (lane < 16) ? wmax[lane] : -1e30f;
        for (int off = 1; off < 16; off <<= 1) mm = fmaxf(mm, __shfl_xor(mm, off));
        if (lane == 0) smax_s = mm;
    }
    __syncthreads();
    float ev = expf(fminf(v - smax_s, 0.f));
    ebuf[tid] = ev;
    g1b[tid] = 1.f / (1.f + expf(-G[(size_t)tid*36 + h*3 + 0]));
    ghb[tid] = 1.f / (1.f + expf(-G[(size_t)tid*36 + h*3 + 1]));
    si_[h*SEQ + tid] = v;
    es_[h*SEQ + tid] = ev;
    __syncthreads();
    if (wv == 0) {
        int base = lane * 16;
        float se = 0.f, ss = 0.f;
        for (int i = 0; i < 16; ++i) { se += ebuf[base + i]; ss += sbuf[base + i]; }
        float pe = se, ps = ss;
        for (int off = 1; off < 64; off <<= 1) {
            float t1 = __shfl_up(pe, off), t2 = __shfl_up(ps, off);
            if (lane >= off) { pe += t1; ps += t2; }
        }
        float E = pe - se, P = ps - ss;   // exclusive prefixes
        for (int i = 0; i < 16; ++i) {
            int l = base + i;
            E += ebuf[l]; P += sbuf[l];
            float t = (float)(l + 1);
            float s1 = g1b[l], sh = ghb[l];
            float a = sh / (E + 1e-12f);
            float b = (s1 - sh) / t;
            float gm = -((b * P + sh) / t);
            al_[h*SEQ + l] = a;
            be_[h*SEQ + l] = b;
            ga_[h*SEQ + l] = gm;
        }
    }
}

// ---------------- K4: causal weighted linear attention + LayerNorm -------------
// 4-way j-split: all 4 waves work the SAME 16-row q-tile (jt strided by wave),
// partial O accumulators combined through LDS, then per-row LayerNorm.
__global__ __launch_bounds__(256) void k_attn(const __hip_bfloat16* __restrict__ Qb,
    const __hip_bfloat16* __restrict__ Kb, const __hip_bfloat16* __restrict__ Vt,
    const float* __restrict__ si_, const float* __restrict__ es_,
    const float* __restrict__ al_, const float* __restrict__ be_,
    const float* __restrict__ ga_, __hip_bfloat16* __restrict__ opre)
{
    int t = blockIdx.x, h = blockIdx.y;   // q-tile 0..63
    int wv = threadIdx.x >> 6, lane = threadIdx.x & 63;
    int g = lane >> 4, n = lane & 15;
    __shared__ short P[4][16*64];
    __shared__ float Op[4][16][64];
    short* Pw = P[wv];
    int m0 = t*16;
    const short* qrow = (const short*)Qb + ((size_t)h*SEQ + m0 + n)*HD + g*8;
    bf16x8 qa0 = *(const bf16x8*)qrow;
    bf16x8 qa1 = *(const bf16x8*)(qrow + 32);
    const float* al = al_ + h*SEQ;
    const float* be = be_ + h*SEQ;
    const float* ga = ga_ + h*SEQ;
    const float* es = es_ + h*SEQ;
    const float* si = si_ + h*SEQ;
    float A_[4], B_[4], G_[4];
    for (int r = 0; r < 4; ++r) {
        int m = m0 + g*4 + r;
        A_[r] = al[m]; B_[r] = be[m]; G_[r] = ga[m];
    }
    f32x4 acco[4];
    for (int et = 0; et < 4; ++et) acco[et] = (f32x4){0.f,0.f,0.f,0.f};

    int jtmax = t >> 2;
    for (int jt = wv; jt <= jtmax; jt += 4) {
        int j0 = jt*64;
        for (int ct = 0; ct < 4; ++ct) {
            const short* krow = (const short*)Kb + ((size_t)h*SEQ + j0 + ct*16 + n)*HD + g*8;
            bf16x8 kb0 = *(const bf16x8*)krow;
            bf16x8 kb1 = *(const bf16x8*)(krow + 32);
            f32x4 sacc = {0.f,0.f,0.f,0.f};
            sacc = __builtin_amdgcn_mfma_f32_16x16x32_bf16(qa0, kb0, sacc, 0, 0, 0);
            sacc = __builtin_amdgcn_mfma_f32_16x16x32_bf16(qa1, kb1, sacc, 0, 0, 0);
            int j = j0 + ct*16 + n;
            float ej = es[j], sj = si[j];
            int chunk = ct*2 + (n>>3), e = n&7;
            for (int r = 0; r < 4; ++r) {
                int m = m0 + g*4 + r;
                float w = (j <= m) ? (A_[r]*ej + B_[r]*sj + G_[r]) : 0.f;
                int ml = g*4 + r;
                Pw[ml*64 + (chunk ^ (ml&7))*8 + e] = f2bs(w * sacc[r]);
            }
        }
        const short* vb = (const short*)Vt + (size_t)h*HD*SEQ;
        for (int et = 0; et < 4; ++et) {
            for (int sub = 0; sub < 2; ++sub) {
                int q = sub*4 + g;
                bf16x8 pa = *(const bf16x8*)(&Pw[n*64 + (q ^ (n&7))*8]);
                bf16x8 vfr = *(const bf16x8*)(vb + (size_t)(et*16 + n)*SEQ + j0 + sub*32 + g*8);
                acco[et] = __builtin_amdgcn_mfma_f32_16x16x32_bf16(pa, vfr, acco[et], 0, 0, 0);
            }
        }
    }
    // stage partials (C-layout: col = lane&15, row = g*4 + r)
    for (int et = 0; et < 4; ++et)
        for (int r = 0; r < 4; ++r)
            Op[wv][g*4 + r][et*16 + n] = acco[et][r];
    __syncthreads();
    // combine + fused LayerNorm; wave wv handles rows wv*4..wv*4+3, lane = e
    for (int rr = 0; rr < 4; ++rr) {
        int row = wv*4 + rr;
        float v = Op[0][row][lane] + Op[1][row][lane] + Op[2][row][lane] + Op[3][row][lane];
        float sm = wave_reduce_sum(v);
        float sq = wave_reduce_sum(v*v);
        float mu = sm * (1.f/64.f);
        float var = fmaxf(sq * (1.f/64.f) - mu*mu, 0.f);
        float invs = rsqrtf(var + 1e-5f);
        opre[(size_t)(m0 + row)*DIM + h*HD + lane] = __float2bfloat16((v - mu) * invs);
    }
}

// ---------------- K5: output projection, 64x64 dbuf GEMM, DMA staging, f32 out -
__global__ __launch_bounds__(256, 4) void k_oproj(const short* __restrict__ A,
    const short* __restrict__ Wob, float* __restrict__ out)
{
    int rt = blockIdx.x, ct = blockIdx.y;
    __shared__ short lds[16384];   // A dbuf @0/4096, B dbuf @8192/12288 (64x64)

    int tid = threadIdx.x;
    int wv = tid>>6, lane = tid&63, g = lane>>4, n = lane&15;
    int wm = wv>>1, wn = wv&1;

    auto dma_step = [&](int buf, int k0) {
        short* Ab = lds + buf*4096;
        short* Bb = lds + 8192 + buf*4096;
        for (int p = 0; p < 2; ++p) {
            int sbase = p*256 + wv*64;
            int s = sbase + lane;
            int r = s >> 3, c = s & 7, cl = c ^ (r & 7);
            const short* ga_ = A + (size_t)(rt*64 + r)*DIM + k0 + cl*8;
            async_copy16(ga_, Ab + sbase*8, lane);
            const short* gb = Wob + (size_t)(ct*64 + r)*DIM + k0 + cl*8;
            async_copy16(gb, Bb + sbase*8, lane);
        }
    };

    f32x4 acc[2][2];
    for (int i=0;i<2;++i) for (int j=0;j<2;++j) acc[i][j] = (f32x4){0,0,0,0};

    dma_step(0, 0);
    for (int it = 0; it < 12; ++it) {
        __syncthreads();
        if (it < 11) dma_step(1 - (it & 1), (it + 1)*64);
        int buf = it & 1;
        const short* Ab = lds + buf*4096;
        const short* Bb = lds + 8192 + buf*4096;
        for (int ks = 0; ks < 2; ++ks) {
            int q = ks*4 + g;
            bf16x8 af[2], bfr[2];
            for (int i=0;i<2;++i)
                af[i] = *(const bf16x8*)(&Ab[((wm*32+i*16+n)*8 + (q ^ (n&7)))*8]);
            for (int j=0;j<2;++j)
                bfr[j] = *(const bf16x8*)(&Bb[((wn*32+j*16+n)*8 + (q ^ (n&7)))*8]);
            for (int i=0;i<2;++i)
                for (int j=0;j<2;++j)
                    acc[i][j] = __builtin_amdgcn_mfma_f32_16x16x32_bf16(af[i], bfr[j], acc[i][j], 0,0,0);
        }
    }
    for (int i=0;i<2;++i) for (int j=0;j<2;++j) for (int r=0;r<4;++r) {
        int row = rt*64 + wm*32 + i*16 + g*4 + r;
        int col = ct*64 + wn*32 + j*16 + n;
        out[(size_t)row*DIM + col] = acc[i][j][r];
    }
}

extern "C" void kernel_launch(void* const* d_in, const int* in_sizes, int n_in,
                              void* d_out, int out_size, void* d_ws, size_t ws_size,
                              hipStream_t stream) {
    const float* X   = (const float*)d_in[0];
    const float* Wq  = (const float*)d_in[1];
    const float* Wk  = (const float*)d_in[2];
    const float* Wv  = (const float*)d_in[3];
    const float* Wu  = (const float*)d_in[4];
    const float* Wg  = (const float*)d_in[5];
    const float* Wo  = (const float*)d_in[6];
    const float* pmu = (const float*)d_in[7];
    const float* plt = (const float*)d_in[8];

    char* w = (char*)d_ws;
    __hip_bfloat16* Qb   = (__hip_bfloat16*)(w + 0);
    __hip_bfloat16* Kb   = (__hip_bfloat16*)(w + 1572864);
    __hip_bfloat16* Vt   = (__hip_bfloat16*)(w + 3145728);
    __hip_bfloat16* opre = (__hip_bfloat16*)(w + 4718592);
    float*          G    = (float*)(w + 6291456);
    float*          si_  = (float*)(w + 6438912);
    float*          es_  = si_ + NH*SEQ;
    float*          al_  = es_ + NH*SEQ;
    float*          be_  = al_ + NH*SEQ;
    float*          ga_  = be_ + NH*SEQ;
    short*          Xb   = (short*)(w + 6684672);
    short*          Wqb  = (short*)(w + 8257536);
    short*          Wkb  = (short*)(w + 9437184);
    short*          Wvb  = (short*)(w + 10616832);
    short*          Wub  = (short*)(w + 11796480);
    short*          Wgb  = (short*)(w + 12976128);
    short*          Wob  = (short*)(w + 13031424);
    __hip_bfloat16* Ub   = (__hip_bfloat16*)d_out;   // scratch; k_oproj overwrites last
    float*          out  = (float*)d_out;

    hipLaunchKernelGGL(k_prep, dim3(384, 7), dim3(256), 0, stream,
                       X, Wq, Wk, Wv, Wu, Wg, Wo, Xb, Wqb, Wkb, Wvb, Wub, Wgb, Wob);
    hipLaunchKernelGGL(k_proj5, dim3(16, 8, 5), dim3(256), 0, stream,
                       Xb, Wqb, Wkb, Wvb, Wub, Wgb, Qb, Kb, Vt, Ub, G);
    hipLaunchKernelGGL(k_scan, dim3(NH), dim3(1024), 0, stream,
                       Ub, G, pmu, plt, si_, es_, al_, be_, ga_);
    hipLaunchKernelGGL(k_attn, dim3(64, NH), dim3(256), 0, stream,
                       Qb, Kb, Vt, si_, es_, al_, be_, ga_, opre);
    hipLaunchKernelGGL(k_oproj, dim3(16, 12), dim3(256), 0, stream,
                       (const short*)opre, Wob, out);
}